// Round 6
// baseline (1528.095 us; speedup 1.0000x reference)
//
#include <hip/hip_runtime.h>
#include <math.h>

typedef __attribute__((ext_vector_type(8))) short short8;
typedef __attribute__((ext_vector_type(4))) float f32x4;
typedef unsigned int uint;
typedef unsigned short ushort;

// Problem constants
#define Lsteps 5
#define Hn 256
#define Wn 256
#define HWn 65536           // 256*256
#define BHW 524288          // 8*65536

// d_out float offsets
#define OUT_IMG    0
#define OUT_FIELDS 524288
#define OUT_RES    5767168
#define OUT_GRADS  8912896

// workspace float offsets
#define WS_IMG   0           // 524288
#define WS_PHIA  524288      // 5242880  [5][8][256][256][2]
#define WS_PHIB  5767168     // 5242880
#define WS_VTMP  11010048    // 1048576  (unused now)
#define WS_W2B   12058624    // 322560 f = 645120 ushort  [5][9 tap][4 kc][7 o][64 lane][8] bf16
#define WS_W3P   12381184    // 5760 f  [5][9 tap][128 ic] fp32
#define WS_X2    12386944    // 27262976 f = 54525952 ushort  [8][256][256][104] bf16

__device__ inline float lrelu(float s) { return s > 0.f ? s : 0.01f * s; }

__device__ inline ushort bf16r(float f) {
  uint u = __float_as_uint(f);
  return (ushort)((u + 0x7fffu + ((u >> 16) & 1u)) >> 16);
}

__device__ inline void make_gauss(float* G) {
  float s = 0.f;
#pragma unroll
  for (int t = 0; t < 15; t++) {
    float d = (float)t - 7.f;
    G[t] = expf(-d * d * (1.f / 32.f));
    s += G[t];
  }
  float inv = 1.f / s;
#pragma unroll
  for (int t = 0; t < 15; t++) G[t] *= inv;
}

__device__ inline float bilin1(const float* __restrict__ p, float x, float y) {
  float x0f = floorf(x), y0f = floorf(y);
  int x0 = (int)x0f, y0 = (int)y0f;
  float fx = x - x0f, fy = y - y0f;
  float w00 = (1.f - fx) * (1.f - fy), w10 = fx * (1.f - fy);
  float w01 = (1.f - fx) * fy, w11 = fx * fy;
  float acc = 0.f;
  if ((unsigned)x0 < 256u && (unsigned)y0 < 256u) acc += w00 * p[y0 * 256 + x0];
  if ((unsigned)(x0 + 1) < 256u && (unsigned)y0 < 256u) acc += w10 * p[y0 * 256 + x0 + 1];
  if ((unsigned)x0 < 256u && (unsigned)(y0 + 1) < 256u) acc += w01 * p[(y0 + 1) * 256 + x0];
  if ((unsigned)(x0 + 1) < 256u && (unsigned)(y0 + 1) < 256u) acc += w11 * p[(y0 + 1) * 256 + x0 + 1];
  return acc;
}

__device__ inline void bilin2(const float* __restrict__ p, float x, float y,
                              float& o0, float& o1) {
  float x0f = floorf(x), y0f = floorf(y);
  int x0 = (int)x0f, y0 = (int)y0f;
  float fx = x - x0f, fy = y - y0f;
  float w00 = (1.f - fx) * (1.f - fy), w10 = fx * (1.f - fy);
  float w01 = (1.f - fx) * fy, w11 = fx * fy;
  o0 = 0.f; o1 = 0.f;
  if ((unsigned)x0 < 256u && (unsigned)y0 < 256u) {
    const float* q = p + (y0 * 256 + x0) * 2; o0 += w00 * q[0]; o1 += w00 * q[1];
  }
  if ((unsigned)(x0 + 1) < 256u && (unsigned)y0 < 256u) {
    const float* q = p + (y0 * 256 + x0 + 1) * 2; o0 += w10 * q[0]; o1 += w10 * q[1];
  }
  if ((unsigned)x0 < 256u && (unsigned)(y0 + 1) < 256u) {
    const float* q = p + ((y0 + 1) * 256 + x0) * 2; o0 += w01 * q[0]; o1 += w01 * q[1];
  }
  if ((unsigned)(x0 + 1) < 256u && (unsigned)(y0 + 1) < 256u) {
    const float* q = p + ((y0 + 1) * 256 + x0 + 1) * 2; o0 += w11 * q[0]; o1 += w11 * q[1];
  }
}

__global__ void init_res0_kernel(const float* __restrict__ z0, float* __restrict__ res0) {
  int idx = blockIdx.x * 256 + threadIdx.x;
  res0[idx] = z0[idx & 65535];
}

// Fragment-ordered bf16 weights: [l][tap][kc][o][lane][8], lane=q*16+n,
// element j (0..7): oc = o*16+n, ic = kc*32+q*8+j. oc/ic>=100 zero-padded.
__global__ void w2b_prep(const float* __restrict__ w2, ushort* __restrict__ w2b) {
  int idx = blockIdx.x * 256 + threadIdx.x;     // 645120
  if (idx >= Lsteps * 129024) return;
  int l = idx / 129024;
  int r = idx - l * 129024;
  int tap = r / 14336;
  int r2 = r - tap * 14336;
  int kc = r2 / 3584;
  int r3 = r2 - kc * 3584;
  int o = r3 >> 9;
  int r4 = r3 & 511;
  int lane = r4 >> 3;
  int j = r4 & 7;
  int q = lane >> 4, n = lane & 15;
  int oc = o * 16 + n;
  int ic = kc * 32 + q * 8 + j;
  float v = (oc < 100 && ic < 100) ? w2[l * 90000 + oc * 900 + ic * 9 + tap] : 0.f;
  w2b[idx] = bf16r(v);
}

// w3p[l][tap][ic] fp32, ic zero-padded to 128
__global__ void w3p_prep(const float* __restrict__ w3, float* __restrict__ w3p) {
  int idx = blockIdx.x * 256 + threadIdx.x;     // 5760
  if (idx >= Lsteps * 9 * 128) return;
  int l = idx / 1152;
  int r = idx - l * 1152;
  int tap = r >> 7;
  int ic = r & 127;
  w3p[idx] = (ic < 100) ? w3[l * 900 + ic * 9 + tap] : 0.f;
}

// Fused sobel + vertical blur + horizontal blur.
// Tile: 64 wide x 16 tall output per block; grid (4,16,8).
__global__ __launch_bounds__(256) void field_fused(
    const float* __restrict__ img, const float* __restrict__ res_i,
    float* __restrict__ grads_i, float* __restrict__ fields_i) {
  __shared__ float sBuf[2560];
  __shared__ float sP[2][2400];
  const int tid = threadIdx.x;
  const int b = blockIdx.z;
  const int Y0 = blockIdx.y * 16, X0 = blockIdx.x * 64;
  float G[15]; make_gauss(G);
  const float* ib = img + b * HWn;
  const float* rb = res_i + b * HWn;

  // stage img rows Y0-8..Y0+23, cols X0-8..X0+71, clamped (replicate pad)
  for (int u = tid; u < 2560; u += 256) {
    int ly = u / 80, lx = u - ly * 80;
    int gy = Y0 - 8 + ly, gx = X0 - 8 + lx;
    gy = gy < 0 ? 0 : (gy > 255 ? 255 : gy);
    gx = gx < 0 ? 0 : (gx > 255 ? 255 : gx);
    sBuf[u] = ib[gy * 256 + gx];
  }
  __syncthreads();

  // p = -res * sobel(img); rows Y0-7..Y0+22 (30), cols X0-7..X0+70 (78 used)
  for (int u = tid; u < 2400; u += 256) {
    int ly = u / 80, lx = u - ly * 80;
    int gy = Y0 - 7 + ly, gx = X0 - 7 + lx;
    float p0 = 0.f, p1 = 0.f;
    if (lx < 78 && (unsigned)gy < 256u && (unsigned)gx < 256u) {
      int base = (ly + 1) * 80 + (lx + 1);
      float a00 = sBuf[base - 81], a01 = sBuf[base - 80], a02 = sBuf[base - 79];
      float a10 = sBuf[base - 1], a12 = sBuf[base + 1];
      float a20 = sBuf[base + 79], a21 = sBuf[base + 80], a22 = sBuf[base + 81];
      float gxs = (a02 - a00 + 2.f * (a12 - a10) + a22 - a20) * 0.125f;
      float gys = (a20 - a00 + 2.f * (a21 - a01) + a22 - a02) * 0.125f;
      float r = rb[gy * 256 + gx];
      p0 = -r * gxs; p1 = -r * gys;
      if (ly >= 7 && ly < 23 && lx >= 7 && lx < 71) {   // owned pixel
        grads_i[b * 131072 + gy * 256 + gx] = gxs;
        grads_i[b * 131072 + 65536 + gy * 256 + gx] = gys;
      }
    }
    sP[0][u] = p0; sP[1][u] = p1;
  }
  __syncthreads();

  // vertical blur -> t (overlays sBuf): 2ch x 16 rows x 80 cols
  for (int u = tid; u < 2560; u += 256) {
    int c = u >= 1280 ? 1 : 0;
    int v = u - c * 1280;
    int ly = v / 80, lx = v - ly * 80;
    float s = 0.f;
    if (lx < 78) {
      const float* pc = &sP[c][ly * 80 + lx];
#pragma unroll
      for (int t = 0; t < 15; t++) s += G[t] * pc[t * 80];
    }
    sBuf[u] = s;
  }
  __syncthreads();

  // horizontal blur -> fields (interleaved 2ch)
  for (int u = tid; u < 2048; u += 256) {
    int c = u >> 10, v = u & 1023;
    int ly = v >> 6, lx = v & 63;
    const float* tc = sBuf + c * 1280 + ly * 80 + lx;
    float s = 0.f;
#pragma unroll
    for (int t = 0; t < 15; t++) s += G[t] * tc[t];
    int gy = Y0 + ly, gx = X0 + lx;
    fields_i[(b * 65536 + gy * 256 + gx) * 2 + c] = s;
  }
}

// Fused conv1 (fp32 VALU -> bf16 LDS) + conv2 (bf16 MFMA).
// Phase B: 2x2 wave partition. Wave (wr,wc) owns pixel-rows wr*4..wr*4+3
// and oc-frags {wc*4..} (4 frags for wc=0, 3 for wc=1). Redundancy is 2x on
// BOTH operand streams (round-1 was 1x A / 4x W -> L2-bound at 19 TB/s;
// round-5 was 4x A / 1x W -> LDS-bound at ~60% pipe + conflicts). A-LDS
// 576 reads/block (~46us pipe), W-L2 2.06 GB/dispatch (~11 TB/s) - neither
// binding. No dead MFMA (2016/block). Per-output accumulation order
// unchanged -> bit-identical.
// Epilogue: acc -> LDS [pixel][104] bf16 -> coalesced uint4 global stores.
// Block: 16x8 pixel tile, 256 threads, LDS 48KB, 3 blocks/CU.
__global__ __launch_bounds__(256, 3) void conv12_kernel(
    const float* __restrict__ res_i, const float* __restrict__ img,
    const float* __restrict__ tgt, const float* __restrict__ w1,
    const short8* __restrict__ w2b, ushort* __restrict__ x2) {
  __shared__ ushort x1s[180 * 136];
  const int tid = threadIdx.x;
  const int b = blockIdx.z;
  const int Y0 = blockIdx.y * 8, X0 = blockIdx.x * 16;
  const float* zb = res_i + b * HWn;
  const float* ib = img + b * HWn;
  const float* tb = tgt + b * HWn;

  // ---- Phase A: conv1 (3->100) + lrelu -> bf16 LDS ----
  if (tid < 180) {
    int ly = tid / 18, lx = tid - ly * 18;
    int gy = Y0 + ly - 1, gx = X0 + lx - 1;
    const bool inb = (unsigned)gy < 256u && (unsigned)gx < 256u;
    float p[27];
#pragma unroll
    for (int dy = 0; dy < 3; dy++)
#pragma unroll
      for (int dx = 0; dx < 3; dx++) {
        int yy = gy + dy - 1, xx = gx + dx - 1;
        bool ok = (unsigned)yy < 256u && (unsigned)xx < 256u;
        int o = ok ? (yy * 256 + xx) : 0;
        int j = dy * 3 + dx;
        p[j] = ok ? zb[o] : 0.f;
        p[9 + j] = ok ? ib[o] : 0.f;
        p[18 + j] = ok ? tb[o] : 0.f;
      }
    const uint base = (uint)tid * 136u;
    for (int oc = 0; oc < 100; oc += 2) {
      const float* wa = w1 + oc * 27;
      float s0 = 0.f, s1 = 0.f;
#pragma unroll
      for (int j = 0; j < 27; j++) {
        s0 = fmaf(p[j], wa[j], s0);
        s1 = fmaf(p[j], wa[27 + j], s1);
      }
      s0 = inb ? lrelu(s0) : 0.f;
      s1 = inb ? lrelu(s1) : 0.f;
      *(uint*)&x1s[base + oc] = (uint)bf16r(s0) | ((uint)bf16r(s1) << 16);
    }
#pragma unroll
    for (int oc = 100; oc < 128; oc += 2) *(uint*)&x1s[base + oc] = 0u;
  }
  __syncthreads();

  // ---- Phase B: conv2 via bf16 MFMA, 2x2 row/oc wave partition ----
  const int lane = tid & 63, wv = tid >> 6;
  const int q = lane >> 4, n = lane & 15;
  const int wr = wv >> 1;            // row-half: pixel rows wr*4..wr*4+3
  const int wc = wv & 1;             // oc-half
  const int o0 = wc * 4;             // first owned oc-frag
  const int NO = wc ? 3 : 4;         // owned frag count (7 = 4+3)

  f32x4 acc[4][4];
#pragma unroll
  for (int r = 0; r < 4; r++)
#pragma unroll
    for (int c = 0; c < 4; c++) acc[r][c] = (f32x4)(0.f);

  const short8* wsrc = w2b + lane + (uint)o0 * 64u;
  // iteration index it = tap*4 + kc, it in [0,36)
  auto loadw = [&](short8 (&dst)[4], int it) {
    const short8* s = wsrc + (it >> 2) * 1792 + (it & 3) * 448;
#pragma unroll
    for (int c = 0; c < 4; c++)
      if (c < NO) dst[c] = s[c * 64];
  };
  auto compute = [&](short8 (&w)[4], int it) {
    const int tap = it >> 2, kc = it & 3;
    const int dy = tap / 3, dx = tap - dy * 3;
    const uint abase = (uint)((dy + wr * 4) * 18 + n + dx) * 136u + (uint)(kc * 32 + q * 8);
    __builtin_amdgcn_s_setprio(1);
#pragma unroll
    for (int r = 0; r < 4; r++) {
      short8 a = *(const short8*)&x1s[abase + (uint)r * 2448u];   // row stride 18*136
#pragma unroll
      for (int c = 0; c < 4; c++)
        if (c < NO)
          acc[r][c] = __builtin_amdgcn_mfma_f32_16x16x32_bf16(a, w[c], acc[r][c], 0, 0, 0);
    }
    __builtin_amdgcn_s_setprio(0);
  };

  short8 wA[4], wB[4];
  loadw(wA, 0);
#pragma unroll
  for (int it = 0; it < 36; it += 2) {
    loadw(wB, it + 1);        // prefetch while computing on wA
    compute(wA, it);
    if (it + 2 < 36) loadw(wA, it + 2);
    compute(wB, it + 1);
  }

  // ---- Epilogue: acc -> LDS [pix(y*16+x)][104] bf16 -> coalesced stores ----
  __syncthreads();   // everyone done reading x1s; safe to repurpose
#pragma unroll
  for (int c = 0; c < 4; c++) {
    if (c < NO) {
      const int oc = (o0 + c) * 16 + n;
      if (oc < 104) {                      // oc 100..103: acc==0 (zero-padded w2b)
#pragma unroll
        for (int r = 0; r < 4; r++) {
#pragma unroll
          for (int v = 0; v < 4; v++) {
            const int pix = (wr * 4 + r) * 16 + q * 4 + v;
            x1s[pix * 104 + oc] = bf16r(lrelu(acc[r][c][v]));
          }
        }
      }
    }
  }
  __syncthreads();
  ushort* xg = x2 + (size_t)((b << 16) + Y0 * 256 + X0) * 104;
  for (int u = tid; u < 1664; u += 256) {   // 128 pixels * 13 uint4
    int pix = u / 13, ch = u - pix * 13;
    int y = pix >> 4, x = pix & 15;
    uint4 val = *(const uint4*)&x1s[pix * 104 + ch * 8];
    *(uint4*)(xg + (size_t)(y * 256 + x) * 104 + ch * 8) = val;
  }
}

// Fused conv3 (100->1, LDS-tiled channels-last bf16 x2) + residual update +
// phi chain + image update.
// Block = 16x16 output pixels (256 threads); x2 halo tile 18x18 px staged
// once into LDS (67.4 KB, 2 blocks/CU) -> global x2 traffic drops 9x.
__global__ __launch_bounds__(256, 2) void cpi_fused(
    const float* __restrict__ res_i,
    const ushort* __restrict__ x2,
    const float* __restrict__ w3p,
    const float* __restrict__ fields_i,
    const float* __restrict__ phi_src,
    float* __restrict__ phi_dst,
    const float* __restrict__ source,
    const float* __restrict__ res_base,
    float* __restrict__ res_n,
    float* __restrict__ img_out, int step) {
  __shared__ ushort sx[324 * 104];   // [18*18 px][104 ch], px stride 208B (16B-aligned)
  const int tid = threadIdx.x;
  const int b = blockIdx.z;
  const int Y0 = blockIdx.y * 16, X0 = blockIdx.x * 16;

  // stage x2 tile + halo (zeros outside image)
  for (int u = tid; u < 4212; u += 256) {     // 324 px * 13 uint4
    int pix = u / 13, ch = u - pix * 13;
    int py = pix / 18, px = pix - py * 18;
    int gy = Y0 - 1 + py, gx = X0 - 1 + px;
    uint4 v = make_uint4(0u, 0u, 0u, 0u);
    if ((unsigned)gy < 256u && (unsigned)gx < 256u)
      v = *(const uint4*)(x2 + (size_t)((b << 16) + gy * 256 + gx) * 104 + ch * 8);
    *(uint4*)&sx[pix * 104 + ch * 8] = v;
  }
  __syncthreads();

  const int ly = tid >> 4, lx = tid & 15;
  const int y = Y0 + ly, x = X0 + lx;
  const int idx = (b << 16) + y * 256 + x;

  // conv3 from LDS tile
  float acc = 0.f;
#pragma unroll
  for (int tap = 0; tap < 9; tap++) {
    int dy = tap / 3, dx = tap - dy * 3;
    const ushort* px_ = &sx[((ly + dy) * 18 + (lx + dx)) * 104];
    const float* wt = w3p + tap * 128;
#pragma unroll
    for (int c = 0; c < 13; c++) {   // 104 channels; 100..103 stored as zero
      uint4 u = *(const uint4*)(px_ + c * 8);
      const float* w8 = wt + c * 8;
      acc = fmaf(__uint_as_float(u.x << 16), w8[0], acc);
      acc = fmaf(__uint_as_float(u.x & 0xffff0000u), w8[1], acc);
      acc = fmaf(__uint_as_float(u.y << 16), w8[2], acc);
      acc = fmaf(__uint_as_float(u.y & 0xffff0000u), w8[3], acc);
      acc = fmaf(__uint_as_float(u.z << 16), w8[4], acc);
      acc = fmaf(__uint_as_float(u.z & 0xffff0000u), w8[5], acc);
      acc = fmaf(__uint_as_float(u.w << 16), w8[6], acc);
      acc = fmaf(__uint_as_float(u.w & 0xffff0000u), w8[7], acc);
    }
  }
  float rn = res_i[idx] - 0.2f * acc;
  res_n[idx] = rn;

  // phi chain + image update (phi values kept in registers)
  int pix2 = (y * 256 + x) * 2;
  float f0 = fields_i[2 * idx], f1 = fields_i[2 * idx + 1];
  float dxp = (float)x - f0 * 0.2f;
  float dyp = (float)y - f1 * 0.2f;
  float img = 0.f, rs = rn;
  for (int k = 0; k <= step; k++) {
    float o0, o1;
    if (k == step) { o0 = dxp; o1 = dyp; }
    else bilin2(phi_src + (size_t)(k * 8 + b) * 131072, dxp, dyp, o0, o1);
    float* dst = phi_dst + (size_t)(k * 8 + b) * 131072 + pix2;
    dst[0] = o0; dst[1] = o1;
    if (k == 0) img = bilin1(source + b * HWn, o0, o1);
    else rs += bilin1(res_base + (size_t)k * BHW + b * HWn, o0, o1);
  }
  img_out[idx] = img + rs * 8.0e-5f;
}

extern "C" void kernel_launch(void* const* d_in, const int* in_sizes, int n_in,
                              void* d_out, int out_size, void* d_ws, size_t ws_size,
                              hipStream_t stream) {
  const float* source = (const float*)d_in[0];
  const float* target = (const float*)d_in[1];
  const float* z0 = (const float*)d_in[3];
  const float* w1 = (const float*)d_in[4];
  const float* w2 = (const float*)d_in[5];
  const float* w3 = (const float*)d_in[6];
  float* out = (float*)d_out;
  float* ws = (float*)d_ws;

  float* ws_img = ws + WS_IMG;
  float* phiA = ws + WS_PHIA;
  float* phiB = ws + WS_PHIB;
  ushort* w2b = (ushort*)(ws + WS_W2B);
  float* w3p = ws + WS_W3P;
  ushort* x2 = (ushort*)(ws + WS_X2);

  hipMemcpyAsync(ws_img, source, BHW * sizeof(float), hipMemcpyDeviceToDevice, stream);
  init_res0_kernel<<<BHW / 256, 256, 0, stream>>>(z0, out + OUT_RES);
  w2b_prep<<<(Lsteps * 129024 + 255) / 256, 256, 0, stream>>>(w2, w2b);
  w3p_prep<<<23, 256, 0, stream>>>(w3, w3p);

  for (int i = 0; i < Lsteps; i++) {
    float* grads_i = out + OUT_GRADS + (size_t)i * 1048576;
    float* fields_i = out + OUT_FIELDS + (size_t)i * 1048576;
    const float* res_i = out + OUT_RES + (size_t)i * BHW;
    float* res_n = out + OUT_RES + (size_t)(i + 1) * BHW;
    float* phi_dst = (i % 2 == 0) ? phiA : phiB;
    float* phi_src = (i % 2 == 0) ? phiB : phiA;

    field_fused<<<dim3(4, 16, 8), 256, 0, stream>>>(ws_img, res_i, grads_i, fields_i);
    conv12_kernel<<<dim3(16, 32, 8), 256, 0, stream>>>(
        res_i, ws_img, target, w1 + i * 2700,
        (const short8*)(w2b + (size_t)i * 129024), x2);
    cpi_fused<<<dim3(16, 16, 8), 256, 0, stream>>>(
        res_i, x2, w3p + i * 1152, fields_i, phi_src, phi_dst,
        source, out + OUT_RES, res_n, ws_img, i);
  }
  hipMemcpyAsync(out + OUT_IMG, ws_img, BHW * sizeof(float), hipMemcpyDeviceToDevice, stream);
}

// Round 7
// 1451.861 us; speedup vs baseline: 1.0525x; 1.0525x over previous
//
#include <hip/hip_runtime.h>
#include <math.h>

typedef __attribute__((ext_vector_type(8))) short short8;
typedef __attribute__((ext_vector_type(4))) float f32x4;
typedef unsigned int uint;
typedef unsigned short ushort;

// Problem constants
#define Lsteps 5
#define Hn 256
#define Wn 256
#define HWn 65536           // 256*256
#define BHW 524288          // 8*65536

// d_out float offsets
#define OUT_IMG    0
#define OUT_FIELDS 524288
#define OUT_RES    5767168
#define OUT_GRADS  8912896

// workspace float offsets
#define WS_IMG   0           // 524288
#define WS_PHIA  524288      // 5242880  [5][8][256][256][2]
#define WS_PHIB  5767168     // 5242880
#define WS_VTMP  11010048    // 1048576  (unused now)
#define WS_W2B   12058624    // 322560 f = 645120 ushort  [5][9 tap][4 kc][7 o][64 lane][8] bf16
#define WS_W3P   12381184    // 5760 f  [5][9 tap][128 ic] fp32
#define WS_X2    12386944    // 27262976 f = 54525952 ushort  [8][256][256][104] bf16

__device__ inline float lrelu(float s) { return s > 0.f ? s : 0.01f * s; }

__device__ inline ushort bf16r(float f) {
  uint u = __float_as_uint(f);
  return (ushort)((u + 0x7fffu + ((u >> 16) & 1u)) >> 16);
}

__device__ inline void make_gauss(float* G) {
  float s = 0.f;
#pragma unroll
  for (int t = 0; t < 15; t++) {
    float d = (float)t - 7.f;
    G[t] = expf(-d * d * (1.f / 32.f));
    s += G[t];
  }
  float inv = 1.f / s;
#pragma unroll
  for (int t = 0; t < 15; t++) G[t] *= inv;
}

__device__ inline float bilin1(const float* __restrict__ p, float x, float y) {
  float x0f = floorf(x), y0f = floorf(y);
  int x0 = (int)x0f, y0 = (int)y0f;
  float fx = x - x0f, fy = y - y0f;
  float w00 = (1.f - fx) * (1.f - fy), w10 = fx * (1.f - fy);
  float w01 = (1.f - fx) * fy, w11 = fx * fy;
  float acc = 0.f;
  if ((unsigned)x0 < 256u && (unsigned)y0 < 256u) acc += w00 * p[y0 * 256 + x0];
  if ((unsigned)(x0 + 1) < 256u && (unsigned)y0 < 256u) acc += w10 * p[y0 * 256 + x0 + 1];
  if ((unsigned)x0 < 256u && (unsigned)(y0 + 1) < 256u) acc += w01 * p[(y0 + 1) * 256 + x0];
  if ((unsigned)(x0 + 1) < 256u && (unsigned)(y0 + 1) < 256u) acc += w11 * p[(y0 + 1) * 256 + x0 + 1];
  return acc;
}

__device__ inline void bilin2(const float* __restrict__ p, float x, float y,
                              float& o0, float& o1) {
  float x0f = floorf(x), y0f = floorf(y);
  int x0 = (int)x0f, y0 = (int)y0f;
  float fx = x - x0f, fy = y - y0f;
  float w00 = (1.f - fx) * (1.f - fy), w10 = fx * (1.f - fy);
  float w01 = (1.f - fx) * fy, w11 = fx * fy;
  o0 = 0.f; o1 = 0.f;
  if ((unsigned)x0 < 256u && (unsigned)y0 < 256u) {
    const float* q = p + (y0 * 256 + x0) * 2; o0 += w00 * q[0]; o1 += w00 * q[1];
  }
  if ((unsigned)(x0 + 1) < 256u && (unsigned)y0 < 256u) {
    const float* q = p + (y0 * 256 + x0 + 1) * 2; o0 += w10 * q[0]; o1 += w10 * q[1];
  }
  if ((unsigned)x0 < 256u && (unsigned)(y0 + 1) < 256u) {
    const float* q = p + ((y0 + 1) * 256 + x0) * 2; o0 += w01 * q[0]; o1 += w01 * q[1];
  }
  if ((unsigned)(x0 + 1) < 256u && (unsigned)(y0 + 1) < 256u) {
    const float* q = p + ((y0 + 1) * 256 + x0 + 1) * 2; o0 += w11 * q[0]; o1 += w11 * q[1];
  }
}

__global__ void init_res0_kernel(const float* __restrict__ z0, float* __restrict__ res0) {
  int idx = blockIdx.x * 256 + threadIdx.x;
  res0[idx] = z0[idx & 65535];
}

// Fragment-ordered bf16 weights: [l][tap][kc][o][lane][8], lane=q*16+n,
// element j (0..7): oc = o*16+n. For kc 0..2: ic = kc*32+q*8+j (0..95).
// For kc==3 (the tail chunk): ic = 72+q*8+j (72..103), weight is ZERO for
// ic 72..95 (already covered by kc=2) and real only for ic 96..99 -> lets
// conv12 store x1 only 104 channels wide (LDS 37.4 KB -> 4 blocks/CU).
__global__ void w2b_prep(const float* __restrict__ w2, ushort* __restrict__ w2b) {
  int idx = blockIdx.x * 256 + threadIdx.x;     // 645120
  if (idx >= Lsteps * 129024) return;
  int l = idx / 129024;
  int r = idx - l * 129024;
  int tap = r / 14336;
  int r2 = r - tap * 14336;
  int kc = r2 / 3584;
  int r3 = r2 - kc * 3584;
  int o = r3 >> 9;
  int r4 = r3 & 511;
  int lane = r4 >> 3;
  int j = r4 & 7;
  int q = lane >> 4, n = lane & 15;
  int oc = o * 16 + n;
  int ic = (kc < 3 ? kc * 32 : 72) + q * 8 + j;
  bool real = (oc < 100) && (kc < 3 ? true : (ic >= 96 && ic < 100));
  float v = real ? w2[l * 90000 + oc * 900 + ic * 9 + tap] : 0.f;
  w2b[idx] = bf16r(v);
}

// w3p[l][tap][ic] fp32, ic zero-padded to 128
__global__ void w3p_prep(const float* __restrict__ w3, float* __restrict__ w3p) {
  int idx = blockIdx.x * 256 + threadIdx.x;     // 5760
  if (idx >= Lsteps * 9 * 128) return;
  int l = idx / 1152;
  int r = idx - l * 1152;
  int tap = r >> 7;
  int ic = r & 127;
  w3p[idx] = (ic < 100) ? w3[l * 900 + ic * 9 + tap] : 0.f;
}

// Fused sobel + vertical blur + horizontal blur.
// Tile: 64 wide x 16 tall output per block; grid (4,16,8).
__global__ __launch_bounds__(256) void field_fused(
    const float* __restrict__ img, const float* __restrict__ res_i,
    float* __restrict__ grads_i, float* __restrict__ fields_i) {
  __shared__ float sBuf[2560];
  __shared__ float sP[2][2400];
  const int tid = threadIdx.x;
  const int b = blockIdx.z;
  const int Y0 = blockIdx.y * 16, X0 = blockIdx.x * 64;
  float G[15]; make_gauss(G);
  const float* ib = img + b * HWn;
  const float* rb = res_i + b * HWn;

  // stage img rows Y0-8..Y0+23, cols X0-8..X0+71, clamped (replicate pad)
  for (int u = tid; u < 2560; u += 256) {
    int ly = u / 80, lx = u - ly * 80;
    int gy = Y0 - 8 + ly, gx = X0 - 8 + lx;
    gy = gy < 0 ? 0 : (gy > 255 ? 255 : gy);
    gx = gx < 0 ? 0 : (gx > 255 ? 255 : gx);
    sBuf[u] = ib[gy * 256 + gx];
  }
  __syncthreads();

  // p = -res * sobel(img); rows Y0-7..Y0+22 (30), cols X0-7..X0+70 (78 used)
  for (int u = tid; u < 2400; u += 256) {
    int ly = u / 80, lx = u - ly * 80;
    int gy = Y0 - 7 + ly, gx = X0 - 7 + lx;
    float p0 = 0.f, p1 = 0.f;
    if (lx < 78 && (unsigned)gy < 256u && (unsigned)gx < 256u) {
      int base = (ly + 1) * 80 + (lx + 1);
      float a00 = sBuf[base - 81], a01 = sBuf[base - 80], a02 = sBuf[base - 79];
      float a10 = sBuf[base - 1], a12 = sBuf[base + 1];
      float a20 = sBuf[base + 79], a21 = sBuf[base + 80], a22 = sBuf[base + 81];
      float gxs = (a02 - a00 + 2.f * (a12 - a10) + a22 - a20) * 0.125f;
      float gys = (a20 - a00 + 2.f * (a21 - a01) + a22 - a02) * 0.125f;
      float r = rb[gy * 256 + gx];
      p0 = -r * gxs; p1 = -r * gys;
      if (ly >= 7 && ly < 23 && lx >= 7 && lx < 71) {   // owned pixel
        grads_i[b * 131072 + gy * 256 + gx] = gxs;
        grads_i[b * 131072 + 65536 + gy * 256 + gx] = gys;
      }
    }
    sP[0][u] = p0; sP[1][u] = p1;
  }
  __syncthreads();

  // vertical blur -> t (overlays sBuf): 2ch x 16 rows x 80 cols
  for (int u = tid; u < 2560; u += 256) {
    int c = u >= 1280 ? 1 : 0;
    int v = u - c * 1280;
    int ly = v / 80, lx = v - ly * 80;
    float s = 0.f;
    if (lx < 78) {
      const float* pc = &sP[c][ly * 80 + lx];
#pragma unroll
      for (int t = 0; t < 15; t++) s += G[t] * pc[t * 80];
    }
    sBuf[u] = s;
  }
  __syncthreads();

  // horizontal blur -> fields (interleaved 2ch)
  for (int u = tid; u < 2048; u += 256) {
    int c = u >> 10, v = u & 1023;
    int ly = v >> 6, lx = v & 63;
    const float* tc = sBuf + c * 1280 + ly * 80 + lx;
    float s = 0.f;
#pragma unroll
    for (int t = 0; t < 15; t++) s += G[t] * tc[t];
    int gy = Y0 + ly, gx = X0 + lx;
    fields_i[(b * 65536 + gy * 256 + gx) * 2 + c] = s;
  }
}

// Fused conv1 (fp32 VALU -> bf16 LDS) + conv2 (bf16 MFMA).
// Phase B: r5-best oc-split (wave w owns oc-frags {2w,2w+1}, all 8 rows;
// weight L2 stream 1.03 GB/dispatch). NEW: x1s rows are 104 channels wide
// (not 136): the kc=3 K-chunk reads channels 72..103 with weights zeroed
// for 72..95 (covered by kc=2) -> bit-identical, 16B-aligned, same
// bank-alias class as 136. LDS 48.96 -> 37.44 KB => 4 blocks/CU (16 waves)
// -- the occupancy was the binding constraint (all partition variants
// pinned at ~220us with no pipe >40%).
// Epilogue: acc -> LDS [pixel][104] bf16 -> coalesced uint4 global stores.
// Block: 16x8 pixel tile, 256 threads, LDS 37.44 KB, 4 blocks/CU.
__global__ __launch_bounds__(256, 4) void conv12_kernel(
    const float* __restrict__ res_i, const float* __restrict__ img,
    const float* __restrict__ tgt, const float* __restrict__ w1,
    const short8* __restrict__ w2b, ushort* __restrict__ x2) {
  __shared__ ushort x1s[180 * 104];
  const int tid = threadIdx.x;
  const int b = blockIdx.z;
  const int Y0 = blockIdx.y * 8, X0 = blockIdx.x * 16;
  const float* zb = res_i + b * HWn;
  const float* ib = img + b * HWn;
  const float* tb = tgt + b * HWn;

  // ---- Phase A: conv1 (3->100) + lrelu -> bf16 LDS (104-wide rows) ----
  if (tid < 180) {
    int ly = tid / 18, lx = tid - ly * 18;
    int gy = Y0 + ly - 1, gx = X0 + lx - 1;
    const bool inb = (unsigned)gy < 256u && (unsigned)gx < 256u;
    float p[27];
#pragma unroll
    for (int dy = 0; dy < 3; dy++)
#pragma unroll
      for (int dx = 0; dx < 3; dx++) {
        int yy = gy + dy - 1, xx = gx + dx - 1;
        bool ok = (unsigned)yy < 256u && (unsigned)xx < 256u;
        int o = ok ? (yy * 256 + xx) : 0;
        int j = dy * 3 + dx;
        p[j] = ok ? zb[o] : 0.f;
        p[9 + j] = ok ? ib[o] : 0.f;
        p[18 + j] = ok ? tb[o] : 0.f;
      }
    const uint base = (uint)tid * 104u;
    for (int oc = 0; oc < 100; oc += 2) {
      const float* wa = w1 + oc * 27;
      float s0 = 0.f, s1 = 0.f;
#pragma unroll
      for (int j = 0; j < 27; j++) {
        s0 = fmaf(p[j], wa[j], s0);
        s1 = fmaf(p[j], wa[27 + j], s1);
      }
      s0 = inb ? lrelu(s0) : 0.f;
      s1 = inb ? lrelu(s1) : 0.f;
      *(uint*)&x1s[base + oc] = (uint)bf16r(s0) | ((uint)bf16r(s1) << 16);
    }
    *(uint*)&x1s[base + 100] = 0u;
    *(uint*)&x1s[base + 102] = 0u;
  }
  __syncthreads();

  // ---- Phase B: conv2 via bf16 MFMA, oc-split across waves ----
  const int lane = tid & 63, wv = tid >> 6;
  const int q = lane >> 4, n = lane & 15;
  f32x4 acc[8][2];
#pragma unroll
  for (int r = 0; r < 8; r++)
#pragma unroll
    for (int f = 0; f < 2; f++) acc[r][f] = (f32x4)(0.f);

  // wave w loads fragments o = 2w, 2w+1 only (disjoint across waves)
  const short8* wsrc = w2b + lane + (uint)(wv * 2) * 64u;
  auto loadw = [&](short8 (&dst)[2], int it) {
    const short8* s = wsrc + (it >> 2) * 1792 + (it & 3) * 448;
    dst[0] = s[0];
    dst[1] = s[64];   // for wv==3 this is a dead fragment (never stored)
  };
  auto compute = [&](short8 (&w)[2], int it) {
    const int tap = it >> 2, kc = it & 3;
    const int dy = tap / 3, dx = tap - dy * 3;
    const int koff = (kc < 3 ? kc * 32 : 72) + q * 8;   // tail chunk at ch 72..103
    const uint abase = (uint)(dy * 18 + n + dx) * 104u + (uint)koff;
    __builtin_amdgcn_s_setprio(1);
#pragma unroll
    for (int r = 0; r < 8; r++) {
      short8 a = *(const short8*)&x1s[abase + (uint)r * 1872u];   // row stride 18*104
      acc[r][0] = __builtin_amdgcn_mfma_f32_16x16x32_bf16(a, w[0], acc[r][0], 0, 0, 0);
      acc[r][1] = __builtin_amdgcn_mfma_f32_16x16x32_bf16(a, w[1], acc[r][1], 0, 0, 0);
    }
    __builtin_amdgcn_s_setprio(0);
  };

  short8 wA[2], wB[2];
  loadw(wA, 0);
#pragma unroll
  for (int it = 0; it < 36; it += 2) {
    loadw(wB, it + 1);        // prefetch while computing on wA
    compute(wA, it);
    if (it + 2 < 36) loadw(wA, it + 2);
    compute(wB, it + 1);
  }

  // ---- Epilogue: acc -> LDS [pix(y*16+x)][104] bf16 -> coalesced stores ----
  __syncthreads();   // everyone done reading x1s; safe to repurpose
#pragma unroll
  for (int f = 0; f < 2; f++) {
    const int o = wv * 2 + f;
    if (o < 7) {
      const int oc = o * 16 + n;
      if (oc < 104) {                      // oc 100..103: acc==0 (zero-padded w2b)
#pragma unroll
        for (int r = 0; r < 8; r++) {
#pragma unroll
          for (int v = 0; v < 4; v++) {
            const int pix = r * 16 + q * 4 + v;
            x1s[pix * 104 + oc] = bf16r(lrelu(acc[r][f][v]));
          }
        }
      }
    }
  }
  __syncthreads();
  ushort* xg = x2 + (size_t)((b << 16) + Y0 * 256 + X0) * 104;
  for (int u = tid; u < 1664; u += 256) {   // 128 pixels * 13 uint4
    int pix = u / 13, ch = u - pix * 13;
    int y = pix >> 4, x = pix & 15;
    uint4 val = *(const uint4*)&x1s[pix * 104 + ch * 8];
    *(uint4*)(xg + (size_t)(y * 256 + x) * 104 + ch * 8) = val;
  }
}

// Fused conv3 (100->1, LDS-tiled channels-last bf16 x2) + residual update +
// phi chain + image update.
// Block = 16x16 output pixels (256 threads); x2 halo tile 18x18 px staged
// once into LDS (67.4 KB, 2 blocks/CU) -> global x2 traffic drops 9x.
__global__ __launch_bounds__(256, 2) void cpi_fused(
    const float* __restrict__ res_i,
    const ushort* __restrict__ x2,
    const float* __restrict__ w3p,
    const float* __restrict__ fields_i,
    const float* __restrict__ phi_src,
    float* __restrict__ phi_dst,
    const float* __restrict__ source,
    const float* __restrict__ res_base,
    float* __restrict__ res_n,
    float* __restrict__ img_out, int step) {
  __shared__ ushort sx[324 * 104];   // [18*18 px][104 ch], px stride 208B (16B-aligned)
  const int tid = threadIdx.x;
  const int b = blockIdx.z;
  const int Y0 = blockIdx.y * 16, X0 = blockIdx.x * 16;

  // stage x2 tile + halo (zeros outside image)
  for (int u = tid; u < 4212; u += 256) {     // 324 px * 13 uint4
    int pix = u / 13, ch = u - pix * 13;
    int py = pix / 18, px = pix - py * 18;
    int gy = Y0 - 1 + py, gx = X0 - 1 + px;
    uint4 v = make_uint4(0u, 0u, 0u, 0u);
    if ((unsigned)gy < 256u && (unsigned)gx < 256u)
      v = *(const uint4*)(x2 + (size_t)((b << 16) + gy * 256 + gx) * 104 + ch * 8);
    *(uint4*)&sx[pix * 104 + ch * 8] = v;
  }
  __syncthreads();

  const int ly = tid >> 4, lx = tid & 15;
  const int y = Y0 + ly, x = X0 + lx;
  const int idx = (b << 16) + y * 256 + x;

  // conv3 from LDS tile
  float acc = 0.f;
#pragma unroll
  for (int tap = 0; tap < 9; tap++) {
    int dy = tap / 3, dx = tap - dy * 3;
    const ushort* px_ = &sx[((ly + dy) * 18 + (lx + dx)) * 104];
    const float* wt = w3p + tap * 128;
#pragma unroll
    for (int c = 0; c < 13; c++) {   // 104 channels; 100..103 stored as zero
      uint4 u = *(const uint4*)(px_ + c * 8);
      const float* w8 = wt + c * 8;
      acc = fmaf(__uint_as_float(u.x << 16), w8[0], acc);
      acc = fmaf(__uint_as_float(u.x & 0xffff0000u), w8[1], acc);
      acc = fmaf(__uint_as_float(u.y << 16), w8[2], acc);
      acc = fmaf(__uint_as_float(u.y & 0xffff0000u), w8[3], acc);
      acc = fmaf(__uint_as_float(u.z << 16), w8[4], acc);
      acc = fmaf(__uint_as_float(u.z & 0xffff0000u), w8[5], acc);
      acc = fmaf(__uint_as_float(u.w << 16), w8[6], acc);
      acc = fmaf(__uint_as_float(u.w & 0xffff0000u), w8[7], acc);
    }
  }
  float rn = res_i[idx] - 0.2f * acc;
  res_n[idx] = rn;

  // phi chain + image update (phi values kept in registers)
  int pix2 = (y * 256 + x) * 2;
  float f0 = fields_i[2 * idx], f1 = fields_i[2 * idx + 1];
  float dxp = (float)x - f0 * 0.2f;
  float dyp = (float)y - f1 * 0.2f;
  float img = 0.f, rs = rn;
  for (int k = 0; k <= step; k++) {
    float o0, o1;
    if (k == step) { o0 = dxp; o1 = dyp; }
    else bilin2(phi_src + (size_t)(k * 8 + b) * 131072, dxp, dyp, o0, o1);
    float* dst = phi_dst + (size_t)(k * 8 + b) * 131072 + pix2;
    dst[0] = o0; dst[1] = o1;
    if (k == 0) img = bilin1(source + b * HWn, o0, o1);
    else rs += bilin1(res_base + (size_t)k * BHW + b * HWn, o0, o1);
  }
  img_out[idx] = img + rs * 8.0e-5f;
}

extern "C" void kernel_launch(void* const* d_in, const int* in_sizes, int n_in,
                              void* d_out, int out_size, void* d_ws, size_t ws_size,
                              hipStream_t stream) {
  const float* source = (const float*)d_in[0];
  const float* target = (const float*)d_in[1];
  const float* z0 = (const float*)d_in[3];
  const float* w1 = (const float*)d_in[4];
  const float* w2 = (const float*)d_in[5];
  const float* w3 = (const float*)d_in[6];
  float* out = (float*)d_out;
  float* ws = (float*)d_ws;

  float* ws_img = ws + WS_IMG;
  float* phiA = ws + WS_PHIA;
  float* phiB = ws + WS_PHIB;
  ushort* w2b = (ushort*)(ws + WS_W2B);
  float* w3p = ws + WS_W3P;
  ushort* x2 = (ushort*)(ws + WS_X2);

  hipMemcpyAsync(ws_img, source, BHW * sizeof(float), hipMemcpyDeviceToDevice, stream);
  init_res0_kernel<<<BHW / 256, 256, 0, stream>>>(z0, out + OUT_RES);
  w2b_prep<<<(Lsteps * 129024 + 255) / 256, 256, 0, stream>>>(w2, w2b);
  w3p_prep<<<23, 256, 0, stream>>>(w3, w3p);

  for (int i = 0; i < Lsteps; i++) {
    float* grads_i = out + OUT_GRADS + (size_t)i * 1048576;
    float* fields_i = out + OUT_FIELDS + (size_t)i * 1048576;
    const float* res_i = out + OUT_RES + (size_t)i * BHW;
    float* res_n = out + OUT_RES + (size_t)(i + 1) * BHW;
    float* phi_dst = (i % 2 == 0) ? phiA : phiB;
    float* phi_src = (i % 2 == 0) ? phiB : phiA;

    field_fused<<<dim3(4, 16, 8), 256, 0, stream>>>(ws_img, res_i, grads_i, fields_i);
    conv12_kernel<<<dim3(16, 32, 8), 256, 0, stream>>>(
        res_i, ws_img, target, w1 + i * 2700,
        (const short8*)(w2b + (size_t)i * 129024), x2);
    cpi_fused<<<dim3(16, 16, 8), 256, 0, stream>>>(
        res_i, x2, w3p + i * 1152, fields_i, phi_src, phi_dst,
        source, out + OUT_RES, res_n, ws_img, i);
  }
  hipMemcpyAsync(out + OUT_IMG, ws_img, BHW * sizeof(float), hipMemcpyDeviceToDevice, stream);
}

// Round 9
// 1421.628 us; speedup vs baseline: 1.0749x; 1.0213x over previous
//
#include <hip/hip_runtime.h>
#include <math.h>

typedef __attribute__((ext_vector_type(8))) short short8;
typedef __attribute__((ext_vector_type(4))) float f32x4;
typedef unsigned int uint;
typedef unsigned short ushort;

// Problem constants
#define Lsteps 5
#define Hn 256
#define Wn 256
#define HWn 65536           // 256*256
#define BHW 524288          // 8*65536

// d_out float offsets
#define OUT_IMG    0
#define OUT_FIELDS 524288
#define OUT_RES    5767168
#define OUT_GRADS  8912896

// workspace float offsets
#define WS_IMG   0           // 524288
#define WS_PHIA  524288      // 5242880  [5][8][256][256][2]
#define WS_PHIB  5767168     // 5242880
#define WS_VTMP  11010048    // 1048576  (unused now)
#define WS_W2B   12058624    // 322560 f = 645120 ushort  [5][9 tap][4 kc][7 o][64 lane][8] bf16
#define WS_W3P   12381184    // 5760 f  [5][9 tap][128 ic] fp32
#define WS_X2    12386944    // 27262976 f = 54525952 ushort  [8][256][256][104] bf16

__device__ inline float lrelu(float s) { return s > 0.f ? s : 0.01f * s; }

__device__ inline ushort bf16r(float f) {
  uint u = __float_as_uint(f);
  return (ushort)((u + 0x7fffu + ((u >> 16) & 1u)) >> 16);
}

__device__ inline void make_gauss(float* G) {
  float s = 0.f;
#pragma unroll
  for (int t = 0; t < 15; t++) {
    float d = (float)t - 7.f;
    G[t] = expf(-d * d * (1.f / 32.f));
    s += G[t];
  }
  float inv = 1.f / s;
#pragma unroll
  for (int t = 0; t < 15; t++) G[t] *= inv;
}

__device__ inline float bilin1(const float* __restrict__ p, float x, float y) {
  float x0f = floorf(x), y0f = floorf(y);
  int x0 = (int)x0f, y0 = (int)y0f;
  float fx = x - x0f, fy = y - y0f;
  float w00 = (1.f - fx) * (1.f - fy), w10 = fx * (1.f - fy);
  float w01 = (1.f - fx) * fy, w11 = fx * fy;
  float acc = 0.f;
  if ((unsigned)x0 < 256u && (unsigned)y0 < 256u) acc += w00 * p[y0 * 256 + x0];
  if ((unsigned)(x0 + 1) < 256u && (unsigned)y0 < 256u) acc += w10 * p[y0 * 256 + x0 + 1];
  if ((unsigned)x0 < 256u && (unsigned)(y0 + 1) < 256u) acc += w01 * p[(y0 + 1) * 256 + x0];
  if ((unsigned)(x0 + 1) < 256u && (unsigned)(y0 + 1) < 256u) acc += w11 * p[(y0 + 1) * 256 + x0 + 1];
  return acc;
}

__device__ inline void bilin2(const float* __restrict__ p, float x, float y,
                              float& o0, float& o1) {
  float x0f = floorf(x), y0f = floorf(y);
  int x0 = (int)x0f, y0 = (int)y0f;
  float fx = x - x0f, fy = y - y0f;
  float w00 = (1.f - fx) * (1.f - fy), w10 = fx * (1.f - fy);
  float w01 = (1.f - fx) * fy, w11 = fx * fy;
  o0 = 0.f; o1 = 0.f;
  if ((unsigned)x0 < 256u && (unsigned)y0 < 256u) {
    const float* q = p + (y0 * 256 + x0) * 2; o0 += w00 * q[0]; o1 += w00 * q[1];
  }
  if ((unsigned)(x0 + 1) < 256u && (unsigned)y0 < 256u) {
    const float* q = p + (y0 * 256 + x0 + 1) * 2; o0 += w10 * q[0]; o1 += w10 * q[1];
  }
  if ((unsigned)x0 < 256u && (unsigned)(y0 + 1) < 256u) {
    const float* q = p + ((y0 + 1) * 256 + x0) * 2; o0 += w01 * q[0]; o1 += w01 * q[1];
  }
  if ((unsigned)(x0 + 1) < 256u && (unsigned)(y0 + 1) < 256u) {
    const float* q = p + ((y0 + 1) * 256 + x0 + 1) * 2; o0 += w11 * q[0]; o1 += w11 * q[1];
  }
}

__global__ void init_res0_kernel(const float* __restrict__ z0, float* __restrict__ res0) {
  int idx = blockIdx.x * 256 + threadIdx.x;
  res0[idx] = z0[idx & 65535];
}

// Fragment-ordered bf16 weights: [l][tap][kc][o][lane][8], lane=q*16+n,
// element j (0..7): oc = o*16+n. For kc 0..2: ic = kc*32+q*8+j (0..95).
// For kc==3 (the tail chunk): ic = 72+q*8+j (72..103), weight is ZERO for
// ic 72..95 (already covered by kc=2) and real only for ic 96..99 -> lets
// conv12 store x1 only 104 channels wide (LDS 37.4 KB).
__global__ void w2b_prep(const float* __restrict__ w2, ushort* __restrict__ w2b) {
  int idx = blockIdx.x * 256 + threadIdx.x;     // 645120
  if (idx >= Lsteps * 129024) return;
  int l = idx / 129024;
  int r = idx - l * 129024;
  int tap = r / 14336;
  int r2 = r - tap * 14336;
  int kc = r2 / 3584;
  int r3 = r2 - kc * 3584;
  int o = r3 >> 9;
  int r4 = r3 & 511;
  int lane = r4 >> 3;
  int j = r4 & 7;
  int q = lane >> 4, n = lane & 15;
  int oc = o * 16 + n;
  int ic = (kc < 3 ? kc * 32 : 72) + q * 8 + j;
  bool real = (oc < 100) && (kc < 3 ? true : (ic >= 96 && ic < 100));
  float v = real ? w2[l * 90000 + oc * 900 + ic * 9 + tap] : 0.f;
  w2b[idx] = bf16r(v);
}

// w3p[l][tap][ic] fp32, ic zero-padded to 128
__global__ void w3p_prep(const float* __restrict__ w3, float* __restrict__ w3p) {
  int idx = blockIdx.x * 256 + threadIdx.x;     // 5760
  if (idx >= Lsteps * 9 * 128) return;
  int l = idx / 1152;
  int r = idx - l * 1152;
  int tap = r >> 7;
  int ic = r & 127;
  w3p[idx] = (ic < 100) ? w3[l * 900 + ic * 9 + tap] : 0.f;
}

// Fused sobel + vertical blur + horizontal blur.
// Tile: 64 wide x 16 tall output per block; grid (4,16,8).
__global__ __launch_bounds__(256) void field_fused(
    const float* __restrict__ img, const float* __restrict__ res_i,
    float* __restrict__ grads_i, float* __restrict__ fields_i) {
  __shared__ float sBuf[2560];
  __shared__ float sP[2][2400];
  const int tid = threadIdx.x;
  const int b = blockIdx.z;
  const int Y0 = blockIdx.y * 16, X0 = blockIdx.x * 64;
  float G[15]; make_gauss(G);
  const float* ib = img + b * HWn;
  const float* rb = res_i + b * HWn;

  // stage img rows Y0-8..Y0+23, cols X0-8..X0+71, clamped (replicate pad)
  for (int u = tid; u < 2560; u += 256) {
    int ly = u / 80, lx = u - ly * 80;
    int gy = Y0 - 8 + ly, gx = X0 - 8 + lx;
    gy = gy < 0 ? 0 : (gy > 255 ? 255 : gy);
    gx = gx < 0 ? 0 : (gx > 255 ? 255 : gx);
    sBuf[u] = ib[gy * 256 + gx];
  }
  __syncthreads();

  // p = -res * sobel(img); rows Y0-7..Y0+22 (30), cols X0-7..X0+70 (78 used)
  for (int u = tid; u < 2400; u += 256) {
    int ly = u / 80, lx = u - ly * 80;
    int gy = Y0 - 7 + ly, gx = X0 - 7 + lx;
    float p0 = 0.f, p1 = 0.f;
    if (lx < 78 && (unsigned)gy < 256u && (unsigned)gx < 256u) {
      int base = (ly + 1) * 80 + (lx + 1);
      float a00 = sBuf[base - 81], a01 = sBuf[base - 80], a02 = sBuf[base - 79];
      float a10 = sBuf[base - 1], a12 = sBuf[base + 1];
      float a20 = sBuf[base + 79], a21 = sBuf[base + 80], a22 = sBuf[base + 81];
      float gxs = (a02 - a00 + 2.f * (a12 - a10) + a22 - a20) * 0.125f;
      float gys = (a20 - a00 + 2.f * (a21 - a01) + a22 - a02) * 0.125f;
      float r = rb[gy * 256 + gx];
      p0 = -r * gxs; p1 = -r * gys;
      if (ly >= 7 && ly < 23 && lx >= 7 && lx < 71) {   // owned pixel
        grads_i[b * 131072 + gy * 256 + gx] = gxs;
        grads_i[b * 131072 + 65536 + gy * 256 + gx] = gys;
      }
    }
    sP[0][u] = p0; sP[1][u] = p1;
  }
  __syncthreads();

  // vertical blur -> t (overlays sBuf): 2ch x 16 rows x 80 cols
  for (int u = tid; u < 2560; u += 256) {
    int c = u >= 1280 ? 1 : 0;
    int v = u - c * 1280;
    int ly = v / 80, lx = v - ly * 80;
    float s = 0.f;
    if (lx < 78) {
      const float* pc = &sP[c][ly * 80 + lx];
#pragma unroll
      for (int t = 0; t < 15; t++) s += G[t] * pc[t * 80];
    }
    sBuf[u] = s;
  }
  __syncthreads();

  // horizontal blur -> fields (interleaved 2ch)
  for (int u = tid; u < 2048; u += 256) {
    int c = u >> 10, v = u & 1023;
    int ly = v >> 6, lx = v & 63;
    const float* tc = sBuf + c * 1280 + ly * 80 + lx;
    float s = 0.f;
#pragma unroll
    for (int t = 0; t < 15; t++) s += G[t] * tc[t];
    int gy = Y0 + ly, gx = X0 + lx;
    fields_i[(b * 65536 + gy * 256 + gx) * 2 + c] = s;
  }
}

// Fused conv1 (fp32 VALU -> bf16 LDS) + conv2 (bf16 MFMA).
// Phase B: oc-split (wave w owns oc-frags {2w,2w+1}) with a (kc,dx)-major
// loop and a 10-row A-fragment REGISTER CACHE: each wave reads rows 0..9
// once per (kc,dx) -> LDS reads 1152 -> 480 per block (the 63% LDS-busy
// pipe at r7), while weight traffic stays at the proven-light 288KB/block.
// Costs ~56 VGPR -> 3 blocks/CU (LDS would allow 4); testing whether the
// 12-wave plateau was pipe-induced (r1: W-L2, r5: LDS) or intrinsic.
// Accumulation order per output becomes (kc,dx,dy) - fp32 reorder only.
// Epilogue: acc -> LDS [pixel][104] bf16 -> coalesced uint4 global stores.
// Block: 16x8 pixel tile, 256 threads, LDS 37.44 KB.
__global__ __launch_bounds__(256, 3) void conv12_kernel(
    const float* __restrict__ res_i, const float* __restrict__ img,
    const float* __restrict__ tgt, const float* __restrict__ w1,
    const short8* __restrict__ w2b, ushort* __restrict__ x2) {
  __shared__ ushort x1s[180 * 104];
  const int tid = threadIdx.x;
  const int b = blockIdx.z;
  const int Y0 = blockIdx.y * 8, X0 = blockIdx.x * 16;
  const float* zb = res_i + b * HWn;
  const float* ib = img + b * HWn;
  const float* tb = tgt + b * HWn;

  // ---- Phase A: conv1 (3->100) + lrelu -> bf16 LDS (104-wide rows) ----
  if (tid < 180) {
    int ly = tid / 18, lx = tid - ly * 18;
    int gy = Y0 + ly - 1, gx = X0 + lx - 1;
    const bool inb = (unsigned)gy < 256u && (unsigned)gx < 256u;
    float p[27];
#pragma unroll
    for (int dy = 0; dy < 3; dy++)
#pragma unroll
      for (int dx = 0; dx < 3; dx++) {
        int yy = gy + dy - 1, xx = gx + dx - 1;
        bool ok = (unsigned)yy < 256u && (unsigned)xx < 256u;
        int o = ok ? (yy * 256 + xx) : 0;
        int j = dy * 3 + dx;
        p[j] = ok ? zb[o] : 0.f;
        p[9 + j] = ok ? ib[o] : 0.f;
        p[18 + j] = ok ? tb[o] : 0.f;
      }
    const uint base = (uint)tid * 104u;
    for (int oc = 0; oc < 100; oc += 2) {
      const float* wa = w1 + oc * 27;
      float s0 = 0.f, s1 = 0.f;
#pragma unroll
      for (int j = 0; j < 27; j++) {
        s0 = fmaf(p[j], wa[j], s0);
        s1 = fmaf(p[j], wa[27 + j], s1);
      }
      s0 = inb ? lrelu(s0) : 0.f;
      s1 = inb ? lrelu(s1) : 0.f;
      *(uint*)&x1s[base + oc] = (uint)bf16r(s0) | ((uint)bf16r(s1) << 16);
    }
    *(uint*)&x1s[base + 100] = 0u;
    *(uint*)&x1s[base + 102] = 0u;
  }
  __syncthreads();

  // ---- Phase B: conv2 via bf16 MFMA, oc-split + 10-row A register cache ----
  const int lane = tid & 63, wv = tid >> 6;
  const int q = lane >> 4, n = lane & 15;
  f32x4 acc[8][2];
#pragma unroll
  for (int r = 0; r < 8; r++)
#pragma unroll
    for (int f = 0; f < 2; f++) acc[r][f] = (f32x4)(0.f);

  // wave w loads fragments o = 2w, 2w+1 (wv3's second frag is dead; its
  // garbage read/MFMA is never stored - same as r5/r7)
  const short8* wsrc = w2b + lane + (uint)(wv * 2) * 64u;
  short8 wbuf[2][2];
  auto loadw = [&](int slot, int m) {   // m = kc*9 + dx*3 + dy, compile-time
    const int kcw = m / 9, rm = m - kcw * 9;
    const int dxw = rm / 3, dyw = rm - dxw * 3;
    const short8* s = wsrc + (dyw * 3 + dxw) * 1792 + kcw * 448;
    wbuf[slot][0] = s[0];
    wbuf[slot][1] = s[64];
  };
  loadw(0, 0);

#pragma unroll
  for (int kc = 0; kc < 4; kc++) {
    const int koff = (kc < 3 ? kc * 32 : 72) + q * 8;   // tail chunk at ch 72..103
#pragma unroll
    for (int dx = 0; dx < 3; dx++) {
      const uint cb = (uint)(n + dx) * 104u + (uint)koff;
      short8 Ar[10];
#pragma unroll
      for (int rr = 0; rr < 10; rr++)
        Ar[rr] = *(const short8*)&x1s[cb + (uint)rr * 1872u];   // row stride 18*104
#pragma unroll
      for (int dy = 0; dy < 3; dy++) {
        const int m = kc * 9 + dx * 3 + dy;
        if (m + 1 < 36) loadw((m + 1) & 1, m + 1);   // 2-deep weight prefetch
        __builtin_amdgcn_s_setprio(1);
#pragma unroll
        for (int r = 0; r < 8; r++) {
          acc[r][0] = __builtin_amdgcn_mfma_f32_16x16x32_bf16(Ar[dy + r], wbuf[m & 1][0], acc[r][0], 0, 0, 0);
          acc[r][1] = __builtin_amdgcn_mfma_f32_16x16x32_bf16(Ar[dy + r], wbuf[m & 1][1], acc[r][1], 0, 0, 0);
        }
        __builtin_amdgcn_s_setprio(0);
      }
    }
  }

  // ---- Epilogue: acc -> LDS [pix(y*16+x)][104] bf16 -> coalesced stores ----
  __syncthreads();   // everyone done reading x1s; safe to repurpose
#pragma unroll
  for (int f = 0; f < 2; f++) {
    const int o = wv * 2 + f;
    if (o < 7) {
      const int oc = o * 16 + n;
      if (oc < 104) {                      // oc 100..103: acc==0 (zero-padded w2b)
#pragma unroll
        for (int r = 0; r < 8; r++) {
#pragma unroll
          for (int v = 0; v < 4; v++) {
            const int pix = r * 16 + q * 4 + v;
            x1s[pix * 104 + oc] = bf16r(lrelu(acc[r][f][v]));
          }
        }
      }
    }
  }
  __syncthreads();
  ushort* xg = x2 + (size_t)((b << 16) + Y0 * 256 + X0) * 104;
  for (int u = tid; u < 1664; u += 256) {   // 128 pixels * 13 uint4
    int pix = u / 13, ch = u - pix * 13;
    int y = pix >> 4, x = pix & 15;
    uint4 val = *(const uint4*)&x1s[pix * 104 + ch * 8];
    *(uint4*)(xg + (size_t)(y * 256 + x) * 104 + ch * 8) = val;
  }
}

// conv3 (100->1, LDS-tiled channels-last bf16 x2) + residual update.
// Block = 16x16 output pixels; x2 halo tile 18x18 px staged once into LDS.
__global__ __launch_bounds__(256, 2) void conv3res_kernel(
    const float* __restrict__ res_i,
    const ushort* __restrict__ x2,
    const float* __restrict__ w3p,
    float* __restrict__ res_n) {
  __shared__ ushort sx[324 * 104];   // [18*18 px][104 ch], px stride 208B (16B-aligned)
  const int tid = threadIdx.x;
  const int b = blockIdx.z;
  const int Y0 = blockIdx.y * 16, X0 = blockIdx.x * 16;

  // stage x2 tile + halo (zeros outside image)
  for (int u = tid; u < 4212; u += 256) {     // 324 px * 13 uint4
    int pix = u / 13, ch = u - pix * 13;
    int py = pix / 18, px = pix - py * 18;
    int gy = Y0 - 1 + py, gx = X0 - 1 + px;
    uint4 v = make_uint4(0u, 0u, 0u, 0u);
    if ((unsigned)gy < 256u && (unsigned)gx < 256u)
      v = *(const uint4*)(x2 + (size_t)((b << 16) + gy * 256 + gx) * 104 + ch * 8);
    *(uint4*)&sx[pix * 104 + ch * 8] = v;
  }
  __syncthreads();

  const int ly = tid >> 4, lx = tid & 15;
  const int y = Y0 + ly, x = X0 + lx;
  const int idx = (b << 16) + y * 256 + x;

  float acc = 0.f;
#pragma unroll
  for (int tap = 0; tap < 9; tap++) {
    int dy = tap / 3, dx = tap - dy * 3;
    const ushort* px_ = &sx[((ly + dy) * 18 + (lx + dx)) * 104];
    const float* wt = w3p + tap * 128;
#pragma unroll
    for (int c = 0; c < 13; c++) {   // 104 channels; 100..103 stored as zero
      uint4 u = *(const uint4*)(px_ + c * 8);
      const float* w8 = wt + c * 8;
      acc = fmaf(__uint_as_float(u.x << 16), w8[0], acc);
      acc = fmaf(__uint_as_float(u.x & 0xffff0000u), w8[1], acc);
      acc = fmaf(__uint_as_float(u.y << 16), w8[2], acc);
      acc = fmaf(__uint_as_float(u.y & 0xffff0000u), w8[3], acc);
      acc = fmaf(__uint_as_float(u.z << 16), w8[4], acc);
      acc = fmaf(__uint_as_float(u.z & 0xffff0000u), w8[5], acc);
      acc = fmaf(__uint_as_float(u.w << 16), w8[6], acc);
      acc = fmaf(__uint_as_float(u.w & 0xffff0000u), w8[7], acc);
    }
  }
  res_n[idx] = res_i[idx] - 0.2f * acc;
}

// phi chain + image update. No LDS -> high occupancy: the scattered
// bilin1/bilin2 gathers are latency-bound and were starved at 2 blocks/CU
// inside the old fused kernel.
__global__ __launch_bounds__(256) void phiimg_kernel(
    const float* __restrict__ fields_i,
    const float* __restrict__ phi_src,
    float* __restrict__ phi_dst,
    const float* __restrict__ source,
    const float* __restrict__ res_base,
    const float* __restrict__ res_n,
    float* __restrict__ img_out, int step) {
  int idx = blockIdx.x * 256 + threadIdx.x;   // 524288
  int b = idx >> 16, y = (idx >> 8) & 255, x = idx & 255;
  int pix2 = (y * 256 + x) * 2;
  float f0 = fields_i[2 * idx], f1 = fields_i[2 * idx + 1];
  float dxp = (float)x - f0 * 0.2f;
  float dyp = (float)y - f1 * 0.2f;
  float img = 0.f, rs = res_n[idx];
  for (int k = 0; k <= step; k++) {
    float o0, o1;
    if (k == step) { o0 = dxp; o1 = dyp; }
    else bilin2(phi_src + (size_t)(k * 8 + b) * 131072, dxp, dyp, o0, o1);
    float* dst = phi_dst + (size_t)(k * 8 + b) * 131072 + pix2;
    dst[0] = o0; dst[1] = o1;
    if (k == 0) img = bilin1(source + b * HWn, o0, o1);
    else rs += bilin1(res_base + (size_t)k * BHW + b * HWn, o0, o1);
  }
  img_out[idx] = img + rs * 8.0e-5f;
}

extern "C" void kernel_launch(void* const* d_in, const int* in_sizes, int n_in,
                              void* d_out, int out_size, void* d_ws, size_t ws_size,
                              hipStream_t stream) {
  const float* source = (const float*)d_in[0];
  const float* target = (const float*)d_in[1];
  const float* z0 = (const float*)d_in[3];
  const float* w1 = (const float*)d_in[4];
  const float* w2 = (const float*)d_in[5];
  const float* w3 = (const float*)d_in[6];
  float* out = (float*)d_out;
  float* ws = (float*)d_ws;

  float* ws_img = ws + WS_IMG;
  float* phiA = ws + WS_PHIA;
  float* phiB = ws + WS_PHIB;
  ushort* w2b = (ushort*)(ws + WS_W2B);
  float* w3p = ws + WS_W3P;
  ushort* x2 = (ushort*)(ws + WS_X2);

  hipMemcpyAsync(ws_img, source, BHW * sizeof(float), hipMemcpyDeviceToDevice, stream);
  init_res0_kernel<<<BHW / 256, 256, 0, stream>>>(z0, out + OUT_RES);
  w2b_prep<<<(Lsteps * 129024 + 255) / 256, 256, 0, stream>>>(w2, w2b);
  w3p_prep<<<23, 256, 0, stream>>>(w3, w3p);

  for (int i = 0; i < Lsteps; i++) {
    float* grads_i = out + OUT_GRADS + (size_t)i * 1048576;
    float* fields_i = out + OUT_FIELDS + (size_t)i * 1048576;
    const float* res_i = out + OUT_RES + (size_t)i * BHW;
    float* res_n = out + OUT_RES + (size_t)(i + 1) * BHW;
    float* phi_dst = (i % 2 == 0) ? phiA : phiB;
    float* phi_src = (i % 2 == 0) ? phiB : phiA;

    field_fused<<<dim3(4, 16, 8), 256, 0, stream>>>(ws_img, res_i, grads_i, fields_i);
    conv12_kernel<<<dim3(16, 32, 8), 256, 0, stream>>>(
        res_i, ws_img, target, w1 + i * 2700,
        (const short8*)(w2b + (size_t)i * 129024), x2);
    conv3res_kernel<<<dim3(16, 16, 8), 256, 0, stream>>>(
        res_i, x2, w3p + i * 1152, res_n);
    phiimg_kernel<<<BHW / 256, 256, 0, stream>>>(
        fields_i, phi_src, phi_dst, source, out + OUT_RES, res_n, ws_img, i);
  }
  hipMemcpyAsync(out + OUT_IMG, ws_img, BHW * sizeof(float), hipMemcpyDeviceToDevice, stream);
}

// Round 10
// 1404.820 us; speedup vs baseline: 1.0878x; 1.0120x over previous
//
#include <hip/hip_runtime.h>
#include <math.h>

typedef __attribute__((ext_vector_type(8))) short short8;
typedef __attribute__((ext_vector_type(4))) float f32x4;
typedef unsigned int uint;
typedef unsigned short ushort;

// Problem constants
#define Lsteps 5
#define Hn 256
#define Wn 256
#define HWn 65536           // 256*256
#define BHW 524288          // 8*65536

// d_out float offsets
#define OUT_IMG    0
#define OUT_FIELDS 524288
#define OUT_RES    5767168
#define OUT_GRADS  8912896

// workspace float offsets
#define WS_IMG   0           // 524288
#define WS_PHIA  524288      // 5242880  [5][8][256][256][2]
#define WS_PHIB  5767168     // 5242880
#define WS_VTMP  11010048    // 1048576  (unused now)
#define WS_W2B   12058624    // 322560 f = 645120 ushort  [5][9 tap][4 kc][7 o][64 lane][8] bf16
#define WS_W3P   12381184    // 5760 f  [5][9 tap][128 ic] fp32
#define WS_X2    12386944    // 27262976 f = 54525952 ushort  [8][256][256][104] bf16

__device__ inline float lrelu(float s) { return s > 0.f ? s : 0.01f * s; }

__device__ inline ushort bf16r(float f) {
  uint u = __float_as_uint(f);
  return (ushort)((u + 0x7fffu + ((u >> 16) & 1u)) >> 16);
}

__device__ inline void make_gauss(float* G) {
  float s = 0.f;
#pragma unroll
  for (int t = 0; t < 15; t++) {
    float d = (float)t - 7.f;
    G[t] = expf(-d * d * (1.f / 32.f));
    s += G[t];
  }
  float inv = 1.f / s;
#pragma unroll
  for (int t = 0; t < 15; t++) G[t] *= inv;
}

__device__ inline float bilin1(const float* __restrict__ p, float x, float y) {
  float x0f = floorf(x), y0f = floorf(y);
  int x0 = (int)x0f, y0 = (int)y0f;
  float fx = x - x0f, fy = y - y0f;
  float w00 = (1.f - fx) * (1.f - fy), w10 = fx * (1.f - fy);
  float w01 = (1.f - fx) * fy, w11 = fx * fy;
  float acc = 0.f;
  if ((unsigned)x0 < 256u && (unsigned)y0 < 256u) acc += w00 * p[y0 * 256 + x0];
  if ((unsigned)(x0 + 1) < 256u && (unsigned)y0 < 256u) acc += w10 * p[y0 * 256 + x0 + 1];
  if ((unsigned)x0 < 256u && (unsigned)(y0 + 1) < 256u) acc += w01 * p[(y0 + 1) * 256 + x0];
  if ((unsigned)(x0 + 1) < 256u && (unsigned)(y0 + 1) < 256u) acc += w11 * p[(y0 + 1) * 256 + x0 + 1];
  return acc;
}

__device__ inline void bilin2(const float* __restrict__ p, float x, float y,
                              float& o0, float& o1) {
  float x0f = floorf(x), y0f = floorf(y);
  int x0 = (int)x0f, y0 = (int)y0f;
  float fx = x - x0f, fy = y - y0f;
  float w00 = (1.f - fx) * (1.f - fy), w10 = fx * (1.f - fy);
  float w01 = (1.f - fx) * fy, w11 = fx * fy;
  o0 = 0.f; o1 = 0.f;
  if ((unsigned)x0 < 256u && (unsigned)y0 < 256u) {
    const float* q = p + (y0 * 256 + x0) * 2; o0 += w00 * q[0]; o1 += w00 * q[1];
  }
  if ((unsigned)(x0 + 1) < 256u && (unsigned)y0 < 256u) {
    const float* q = p + (y0 * 256 + x0 + 1) * 2; o0 += w10 * q[0]; o1 += w10 * q[1];
  }
  if ((unsigned)x0 < 256u && (unsigned)(y0 + 1) < 256u) {
    const float* q = p + ((y0 + 1) * 256 + x0) * 2; o0 += w01 * q[0]; o1 += w01 * q[1];
  }
  if ((unsigned)(x0 + 1) < 256u && (unsigned)(y0 + 1) < 256u) {
    const float* q = p + ((y0 + 1) * 256 + x0 + 1) * 2; o0 += w11 * q[0]; o1 += w11 * q[1];
  }
}

__global__ void init_res0_kernel(const float* __restrict__ z0, float* __restrict__ res0) {
  int idx = blockIdx.x * 256 + threadIdx.x;
  res0[idx] = z0[idx & 65535];
}

// Fragment-ordered bf16 weights: [l][tap][kc][o][lane][8], lane=q*16+n,
// element j (0..7): oc = o*16+n. For kc 0..2: ic = kc*32+q*8+j (0..95).
// For kc==3 (the tail chunk): ic = 72+q*8+j (72..103), weight is ZERO for
// ic 72..95 (already covered by kc=2) and real only for ic 96..99 -> lets
// conv12 store x1 only 104 channels wide (LDS 37.4 KB -> 4 blocks/CU).
__global__ void w2b_prep(const float* __restrict__ w2, ushort* __restrict__ w2b) {
  int idx = blockIdx.x * 256 + threadIdx.x;     // 645120
  if (idx >= Lsteps * 129024) return;
  int l = idx / 129024;
  int r = idx - l * 129024;
  int tap = r / 14336;
  int r2 = r - tap * 14336;
  int kc = r2 / 3584;
  int r3 = r2 - kc * 3584;
  int o = r3 >> 9;
  int r4 = r3 & 511;
  int lane = r4 >> 3;
  int j = r4 & 7;
  int q = lane >> 4, n = lane & 15;
  int oc = o * 16 + n;
  int ic = (kc < 3 ? kc * 32 : 72) + q * 8 + j;
  bool real = (oc < 100) && (kc < 3 ? true : (ic >= 96 && ic < 100));
  float v = real ? w2[l * 90000 + oc * 900 + ic * 9 + tap] : 0.f;
  w2b[idx] = bf16r(v);
}

// w3p[l][tap][ic] fp32, ic zero-padded to 128
__global__ void w3p_prep(const float* __restrict__ w3, float* __restrict__ w3p) {
  int idx = blockIdx.x * 256 + threadIdx.x;     // 5760
  if (idx >= Lsteps * 9 * 128) return;
  int l = idx / 1152;
  int r = idx - l * 1152;
  int tap = r >> 7;
  int ic = r & 127;
  w3p[idx] = (ic < 100) ? w3[l * 900 + ic * 9 + tap] : 0.f;
}

// Fused sobel + vertical blur + horizontal blur.
// Tile: 64 wide x 16 tall output per block; grid (4,16,8).
__global__ __launch_bounds__(256) void field_fused(
    const float* __restrict__ img, const float* __restrict__ res_i,
    float* __restrict__ grads_i, float* __restrict__ fields_i) {
  __shared__ float sBuf[2560];
  __shared__ float sP[2][2400];
  const int tid = threadIdx.x;
  const int b = blockIdx.z;
  const int Y0 = blockIdx.y * 16, X0 = blockIdx.x * 64;
  float G[15]; make_gauss(G);
  const float* ib = img + b * HWn;
  const float* rb = res_i + b * HWn;

  // stage img rows Y0-8..Y0+23, cols X0-8..X0+71, clamped (replicate pad)
  for (int u = tid; u < 2560; u += 256) {
    int ly = u / 80, lx = u - ly * 80;
    int gy = Y0 - 8 + ly, gx = X0 - 8 + lx;
    gy = gy < 0 ? 0 : (gy > 255 ? 255 : gy);
    gx = gx < 0 ? 0 : (gx > 255 ? 255 : gx);
    sBuf[u] = ib[gy * 256 + gx];
  }
  __syncthreads();

  // p = -res * sobel(img); rows Y0-7..Y0+22 (30), cols X0-7..X0+70 (78 used)
  for (int u = tid; u < 2400; u += 256) {
    int ly = u / 80, lx = u - ly * 80;
    int gy = Y0 - 7 + ly, gx = X0 - 7 + lx;
    float p0 = 0.f, p1 = 0.f;
    if (lx < 78 && (unsigned)gy < 256u && (unsigned)gx < 256u) {
      int base = (ly + 1) * 80 + (lx + 1);
      float a00 = sBuf[base - 81], a01 = sBuf[base - 80], a02 = sBuf[base - 79];
      float a10 = sBuf[base - 1], a12 = sBuf[base + 1];
      float a20 = sBuf[base + 79], a21 = sBuf[base + 80], a22 = sBuf[base + 81];
      float gxs = (a02 - a00 + 2.f * (a12 - a10) + a22 - a20) * 0.125f;
      float gys = (a20 - a00 + 2.f * (a21 - a01) + a22 - a02) * 0.125f;
      float r = rb[gy * 256 + gx];
      p0 = -r * gxs; p1 = -r * gys;
      if (ly >= 7 && ly < 23 && lx >= 7 && lx < 71) {   // owned pixel
        grads_i[b * 131072 + gy * 256 + gx] = gxs;
        grads_i[b * 131072 + 65536 + gy * 256 + gx] = gys;
      }
    }
    sP[0][u] = p0; sP[1][u] = p1;
  }
  __syncthreads();

  // vertical blur -> t (overlays sBuf): 2ch x 16 rows x 80 cols
  for (int u = tid; u < 2560; u += 256) {
    int c = u >= 1280 ? 1 : 0;
    int v = u - c * 1280;
    int ly = v / 80, lx = v - ly * 80;
    float s = 0.f;
    if (lx < 78) {
      const float* pc = &sP[c][ly * 80 + lx];
#pragma unroll
      for (int t = 0; t < 15; t++) s += G[t] * pc[t * 80];
    }
    sBuf[u] = s;
  }
  __syncthreads();

  // horizontal blur -> fields (interleaved 2ch)
  for (int u = tid; u < 2048; u += 256) {
    int c = u >> 10, v = u & 1023;
    int ly = v >> 6, lx = v & 63;
    const float* tc = sBuf + c * 1280 + ly * 80 + lx;
    float s = 0.f;
#pragma unroll
    for (int t = 0; t < 15; t++) s += G[t] * tc[t];
    int gy = Y0 + ly, gx = X0 + lx;
    fields_i[(b * 65536 + gy * 256 + gx) * 2 + c] = s;
  }
}

// Fused conv1 (fp32 VALU -> bf16 LDS) + conv2 (bf16 MFMA).
// ROUND-7 structure (best measured: 197us): oc-split (wave w owns oc-frags
// {2w,2w+1}, all 8 rows; weight L2 stream 1.03 GB/dispatch), x1s rows 104
// channels wide via the kc=3 remap -> LDS 37.44 KB, 4 blocks/CU (16 waves).
// VGPR 60 + AGPR 64 = 124 <= 128/wave unified budget -- do NOT add register
// arrays here: r9's 10-row A-cache (VGPR 72 -> 136 total) fell to 3 blocks
// and regressed to 213us. The ~4.5 conflict-counts per b128 A-read are
// m134's intrinsic b128 throughput gap, not a fixable layout conflict.
// Epilogue: acc -> LDS [pixel][104] bf16 -> coalesced uint4 global stores.
// Block: 16x8 pixel tile, 256 threads, LDS 37.44 KB, 4 blocks/CU.
__global__ __launch_bounds__(256, 4) void conv12_kernel(
    const float* __restrict__ res_i, const float* __restrict__ img,
    const float* __restrict__ tgt, const float* __restrict__ w1,
    const short8* __restrict__ w2b, ushort* __restrict__ x2) {
  __shared__ ushort x1s[180 * 104];
  const int tid = threadIdx.x;
  const int b = blockIdx.z;
  const int Y0 = blockIdx.y * 8, X0 = blockIdx.x * 16;
  const float* zb = res_i + b * HWn;
  const float* ib = img + b * HWn;
  const float* tb = tgt + b * HWn;

  // ---- Phase A: conv1 (3->100) + lrelu -> bf16 LDS (104-wide rows) ----
  if (tid < 180) {
    int ly = tid / 18, lx = tid - ly * 18;
    int gy = Y0 + ly - 1, gx = X0 + lx - 1;
    const bool inb = (unsigned)gy < 256u && (unsigned)gx < 256u;
    float p[27];
#pragma unroll
    for (int dy = 0; dy < 3; dy++)
#pragma unroll
      for (int dx = 0; dx < 3; dx++) {
        int yy = gy + dy - 1, xx = gx + dx - 1;
        bool ok = (unsigned)yy < 256u && (unsigned)xx < 256u;
        int o = ok ? (yy * 256 + xx) : 0;
        int j = dy * 3 + dx;
        p[j] = ok ? zb[o] : 0.f;
        p[9 + j] = ok ? ib[o] : 0.f;
        p[18 + j] = ok ? tb[o] : 0.f;
      }
    const uint base = (uint)tid * 104u;
    for (int oc = 0; oc < 100; oc += 2) {
      const float* wa = w1 + oc * 27;
      float s0 = 0.f, s1 = 0.f;
#pragma unroll
      for (int j = 0; j < 27; j++) {
        s0 = fmaf(p[j], wa[j], s0);
        s1 = fmaf(p[j], wa[27 + j], s1);
      }
      s0 = inb ? lrelu(s0) : 0.f;
      s1 = inb ? lrelu(s1) : 0.f;
      *(uint*)&x1s[base + oc] = (uint)bf16r(s0) | ((uint)bf16r(s1) << 16);
    }
    *(uint*)&x1s[base + 100] = 0u;
    *(uint*)&x1s[base + 102] = 0u;
  }
  __syncthreads();

  // ---- Phase B: conv2 via bf16 MFMA, oc-split across waves ----
  const int lane = tid & 63, wv = tid >> 6;
  const int q = lane >> 4, n = lane & 15;
  f32x4 acc[8][2];
#pragma unroll
  for (int r = 0; r < 8; r++)
#pragma unroll
    for (int f = 0; f < 2; f++) acc[r][f] = (f32x4)(0.f);

  // wave w loads fragments o = 2w, 2w+1 only (disjoint across waves)
  const short8* wsrc = w2b + lane + (uint)(wv * 2) * 64u;
  auto loadw = [&](short8 (&dst)[2], int it) {
    const short8* s = wsrc + (it >> 2) * 1792 + (it & 3) * 448;
    dst[0] = s[0];
    dst[1] = s[64];   // for wv==3 this is a dead fragment (never stored)
  };
  auto compute = [&](short8 (&w)[2], int it) {
    const int tap = it >> 2, kc = it & 3;
    const int dy = tap / 3, dx = tap - dy * 3;
    const int koff = (kc < 3 ? kc * 32 : 72) + q * 8;   // tail chunk at ch 72..103
    const uint abase = (uint)(dy * 18 + n + dx) * 104u + (uint)koff;
    __builtin_amdgcn_s_setprio(1);
#pragma unroll
    for (int r = 0; r < 8; r++) {
      short8 a = *(const short8*)&x1s[abase + (uint)r * 1872u];   // row stride 18*104
      acc[r][0] = __builtin_amdgcn_mfma_f32_16x16x32_bf16(a, w[0], acc[r][0], 0, 0, 0);
      acc[r][1] = __builtin_amdgcn_mfma_f32_16x16x32_bf16(a, w[1], acc[r][1], 0, 0, 0);
    }
    __builtin_amdgcn_s_setprio(0);
  };

  short8 wA[2], wB[2];
  loadw(wA, 0);
#pragma unroll
  for (int it = 0; it < 36; it += 2) {
    loadw(wB, it + 1);        // prefetch while computing on wA
    compute(wA, it);
    if (it + 2 < 36) loadw(wA, it + 2);
    compute(wB, it + 1);
  }

  // ---- Epilogue: acc -> LDS [pix(y*16+x)][104] bf16 -> coalesced stores ----
  __syncthreads();   // everyone done reading x1s; safe to repurpose
#pragma unroll
  for (int f = 0; f < 2; f++) {
    const int o = wv * 2 + f;
    if (o < 7) {
      const int oc = o * 16 + n;
      if (oc < 104) {                      // oc 100..103: acc==0 (zero-padded w2b)
#pragma unroll
        for (int r = 0; r < 8; r++) {
#pragma unroll
          for (int v = 0; v < 4; v++) {
            const int pix = r * 16 + q * 4 + v;
            x1s[pix * 104 + oc] = bf16r(lrelu(acc[r][f][v]));
          }
        }
      }
    }
  }
  __syncthreads();
  ushort* xg = x2 + (size_t)((b << 16) + Y0 * 256 + X0) * 104;
  for (int u = tid; u < 1664; u += 256) {   // 128 pixels * 13 uint4
    int pix = u / 13, ch = u - pix * 13;
    int y = pix >> 4, x = pix & 15;
    uint4 val = *(const uint4*)&x1s[pix * 104 + ch * 8];
    *(uint4*)(xg + (size_t)(y * 256 + x) * 104 + ch * 8) = val;
  }
}

// conv3 (100->1, LDS-tiled channels-last bf16 x2) + residual update.
// Block = 16x16 output pixels; x2 halo tile 18x18 px staged once into LDS.
__global__ __launch_bounds__(256, 2) void conv3res_kernel(
    const float* __restrict__ res_i,
    const ushort* __restrict__ x2,
    const float* __restrict__ w3p,
    float* __restrict__ res_n) {
  __shared__ ushort sx[324 * 104];   // [18*18 px][104 ch], px stride 208B (16B-aligned)
  const int tid = threadIdx.x;
  const int b = blockIdx.z;
  const int Y0 = blockIdx.y * 16, X0 = blockIdx.x * 16;

  // stage x2 tile + halo (zeros outside image)
  for (int u = tid; u < 4212; u += 256) {     // 324 px * 13 uint4
    int pix = u / 13, ch = u - pix * 13;
    int py = pix / 18, px = pix - py * 18;
    int gy = Y0 - 1 + py, gx = X0 - 1 + px;
    uint4 v = make_uint4(0u, 0u, 0u, 0u);
    if ((unsigned)gy < 256u && (unsigned)gx < 256u)
      v = *(const uint4*)(x2 + (size_t)((b << 16) + gy * 256 + gx) * 104 + ch * 8);
    *(uint4*)&sx[pix * 104 + ch * 8] = v;
  }
  __syncthreads();

  const int ly = tid >> 4, lx = tid & 15;
  const int y = Y0 + ly, x = X0 + lx;
  const int idx = (b << 16) + y * 256 + x;

  float acc = 0.f;
#pragma unroll
  for (int tap = 0; tap < 9; tap++) {
    int dy = tap / 3, dx = tap - dy * 3;
    const ushort* px_ = &sx[((ly + dy) * 18 + (lx + dx)) * 104];
    const float* wt = w3p + tap * 128;
#pragma unroll
    for (int c = 0; c < 13; c++) {   // 104 channels; 100..103 stored as zero
      uint4 u = *(const uint4*)(px_ + c * 8);
      const float* w8 = wt + c * 8;
      acc = fmaf(__uint_as_float(u.x << 16), w8[0], acc);
      acc = fmaf(__uint_as_float(u.x & 0xffff0000u), w8[1], acc);
      acc = fmaf(__uint_as_float(u.y << 16), w8[2], acc);
      acc = fmaf(__uint_as_float(u.y & 0xffff0000u), w8[3], acc);
      acc = fmaf(__uint_as_float(u.z << 16), w8[4], acc);
      acc = fmaf(__uint_as_float(u.z & 0xffff0000u), w8[5], acc);
      acc = fmaf(__uint_as_float(u.w << 16), w8[6], acc);
      acc = fmaf(__uint_as_float(u.w & 0xffff0000u), w8[7], acc);
    }
  }
  res_n[idx] = res_i[idx] - 0.2f * acc;
}

// phi chain + image update. No LDS -> high occupancy: the scattered
// bilin1/bilin2 gathers are latency-bound and were starved at 2 blocks/CU
// inside the old fused kernel.
__global__ __launch_bounds__(256) void phiimg_kernel(
    const float* __restrict__ fields_i,
    const float* __restrict__ phi_src,
    float* __restrict__ phi_dst,
    const float* __restrict__ source,
    const float* __restrict__ res_base,
    const float* __restrict__ res_n,
    float* __restrict__ img_out, int step) {
  int idx = blockIdx.x * 256 + threadIdx.x;   // 524288
  int b = idx >> 16, y = (idx >> 8) & 255, x = idx & 255;
  int pix2 = (y * 256 + x) * 2;
  float f0 = fields_i[2 * idx], f1 = fields_i[2 * idx + 1];
  float dxp = (float)x - f0 * 0.2f;
  float dyp = (float)y - f1 * 0.2f;
  float img = 0.f, rs = res_n[idx];
  for (int k = 0; k <= step; k++) {
    float o0, o1;
    if (k == step) { o0 = dxp; o1 = dyp; }
    else bilin2(phi_src + (size_t)(k * 8 + b) * 131072, dxp, dyp, o0, o1);
    float* dst = phi_dst + (size_t)(k * 8 + b) * 131072 + pix2;
    dst[0] = o0; dst[1] = o1;
    if (k == 0) img = bilin1(source + b * HWn, o0, o1);
    else rs += bilin1(res_base + (size_t)k * BHW + b * HWn, o0, o1);
  }
  img_out[idx] = img + rs * 8.0e-5f;
}

extern "C" void kernel_launch(void* const* d_in, const int* in_sizes, int n_in,
                              void* d_out, int out_size, void* d_ws, size_t ws_size,
                              hipStream_t stream) {
  const float* source = (const float*)d_in[0];
  const float* target = (const float*)d_in[1];
  const float* z0 = (const float*)d_in[3];
  const float* w1 = (const float*)d_in[4];
  const float* w2 = (const float*)d_in[5];
  const float* w3 = (const float*)d_in[6];
  float* out = (float*)d_out;
  float* ws = (float*)d_ws;

  float* ws_img = ws + WS_IMG;
  float* phiA = ws + WS_PHIA;
  float* phiB = ws + WS_PHIB;
  ushort* w2b = (ushort*)(ws + WS_W2B);
  float* w3p = ws + WS_W3P;
  ushort* x2 = (ushort*)(ws + WS_X2);

  hipMemcpyAsync(ws_img, source, BHW * sizeof(float), hipMemcpyDeviceToDevice, stream);
  init_res0_kernel<<<BHW / 256, 256, 0, stream>>>(z0, out + OUT_RES);
  w2b_prep<<<(Lsteps * 129024 + 255) / 256, 256, 0, stream>>>(w2, w2b);
  w3p_prep<<<23, 256, 0, stream>>>(w3, w3p);

  for (int i = 0; i < Lsteps; i++) {
    float* grads_i = out + OUT_GRADS + (size_t)i * 1048576;
    float* fields_i = out + OUT_FIELDS + (size_t)i * 1048576;
    const float* res_i = out + OUT_RES + (size_t)i * BHW;
    float* res_n = out + OUT_RES + (size_t)(i + 1) * BHW;
    float* phi_dst = (i % 2 == 0) ? phiA : phiB;
    float* phi_src = (i % 2 == 0) ? phiB : phiA;

    field_fused<<<dim3(4, 16, 8), 256, 0, stream>>>(ws_img, res_i, grads_i, fields_i);
    conv12_kernel<<<dim3(16, 32, 8), 256, 0, stream>>>(
        res_i, ws_img, target, w1 + i * 2700,
        (const short8*)(w2b + (size_t)i * 129024), x2);
    conv3res_kernel<<<dim3(16, 16, 8), 256, 0, stream>>>(
        res_i, x2, w3p + i * 1152, res_n);
    phiimg_kernel<<<BHW / 256, 256, 0, stream>>>(
        fields_i, phi_src, phi_dst, source, out + OUT_RES, res_n, ws_img, i);
  }
  hipMemcpyAsync(out + OUT_IMG, ws_img, BHW * sizeof(float), hipMemcpyDeviceToDevice, stream);
}

// Round 11
// 1338.832 us; speedup vs baseline: 1.1414x; 1.0493x over previous
//
#include <hip/hip_runtime.h>
#include <math.h>

typedef __attribute__((ext_vector_type(8))) short short8;
typedef __attribute__((ext_vector_type(4))) float f32x4;
typedef unsigned int uint;
typedef unsigned short ushort;

// Problem constants
#define Lsteps 5
#define Hn 256
#define Wn 256
#define HWn 65536           // 256*256
#define BHW 524288          // 8*65536

// d_out float offsets
#define OUT_IMG    0
#define OUT_FIELDS 524288
#define OUT_RES    5767168
#define OUT_GRADS  8912896

// workspace float offsets
#define WS_IMG   0           // 524288
#define WS_PHIA  524288      // 5242880  [5][8][256][256][2]
#define WS_PHIB  5767168     // 5242880
#define WS_VTMP  11010048    // 1048576  (unused now)
#define WS_W2B   12058624    // 322560 f = 645120 ushort  [5][9 tap][4 kc][7 o][64 lane][8] bf16
#define WS_W3P   12381184    // 5760 f  [5][9 tap][128 ic] fp32
#define WS_X2    12386944    // 27262976 f = 54525952 ushort  [8][256][256][104] bf16

__device__ inline float lrelu(float s) { return s > 0.f ? s : 0.01f * s; }

__device__ inline ushort bf16r(float f) {
  uint u = __float_as_uint(f);
  return (ushort)((u + 0x7fffu + ((u >> 16) & 1u)) >> 16);
}

__device__ inline void make_gauss(float* G) {
  float s = 0.f;
#pragma unroll
  for (int t = 0; t < 15; t++) {
    float d = (float)t - 7.f;
    G[t] = expf(-d * d * (1.f / 32.f));
    s += G[t];
  }
  float inv = 1.f / s;
#pragma unroll
  for (int t = 0; t < 15; t++) G[t] *= inv;
}

__device__ inline float bilin1(const float* __restrict__ p, float x, float y) {
  float x0f = floorf(x), y0f = floorf(y);
  int x0 = (int)x0f, y0 = (int)y0f;
  float fx = x - x0f, fy = y - y0f;
  float w00 = (1.f - fx) * (1.f - fy), w10 = fx * (1.f - fy);
  float w01 = (1.f - fx) * fy, w11 = fx * fy;
  float acc = 0.f;
  if ((unsigned)x0 < 256u && (unsigned)y0 < 256u) acc += w00 * p[y0 * 256 + x0];
  if ((unsigned)(x0 + 1) < 256u && (unsigned)y0 < 256u) acc += w10 * p[y0 * 256 + x0 + 1];
  if ((unsigned)x0 < 256u && (unsigned)(y0 + 1) < 256u) acc += w01 * p[(y0 + 1) * 256 + x0];
  if ((unsigned)(x0 + 1) < 256u && (unsigned)(y0 + 1) < 256u) acc += w11 * p[(y0 + 1) * 256 + x0 + 1];
  return acc;
}

__device__ inline void bilin2(const float* __restrict__ p, float x, float y,
                              float& o0, float& o1) {
  float x0f = floorf(x), y0f = floorf(y);
  int x0 = (int)x0f, y0 = (int)y0f;
  float fx = x - x0f, fy = y - y0f;
  float w00 = (1.f - fx) * (1.f - fy), w10 = fx * (1.f - fy);
  float w01 = (1.f - fx) * fy, w11 = fx * fy;
  o0 = 0.f; o1 = 0.f;
  if ((unsigned)x0 < 256u && (unsigned)y0 < 256u) {
    const float* q = p + (y0 * 256 + x0) * 2; o0 += w00 * q[0]; o1 += w00 * q[1];
  }
  if ((unsigned)(x0 + 1) < 256u && (unsigned)y0 < 256u) {
    const float* q = p + (y0 * 256 + x0 + 1) * 2; o0 += w10 * q[0]; o1 += w10 * q[1];
  }
  if ((unsigned)x0 < 256u && (unsigned)(y0 + 1) < 256u) {
    const float* q = p + ((y0 + 1) * 256 + x0) * 2; o0 += w01 * q[0]; o1 += w01 * q[1];
  }
  if ((unsigned)(x0 + 1) < 256u && (unsigned)(y0 + 1) < 256u) {
    const float* q = p + ((y0 + 1) * 256 + x0 + 1) * 2; o0 += w11 * q[0]; o1 += w11 * q[1];
  }
}

__global__ void init_res0_kernel(const float* __restrict__ z0, float* __restrict__ res0) {
  int idx = blockIdx.x * 256 + threadIdx.x;
  res0[idx] = z0[idx & 65535];
}

// Fragment-ordered bf16 weights: [l][tap][kc][o][lane][8], lane=q*16+n,
// element j (0..7): oc = o*16+n. For kc 0..2: ic = kc*32+q*8+j (0..95).
// For kc==3 (the tail chunk): ic = 72+q*8+j (72..103), weight is ZERO for
// ic 72..95 (already covered by kc=2) and real only for ic 96..99 -> lets
// conv12 store x1 only 104 channels wide (LDS 37.4 KB -> 4 blocks/CU).
__global__ void w2b_prep(const float* __restrict__ w2, ushort* __restrict__ w2b) {
  int idx = blockIdx.x * 256 + threadIdx.x;     // 645120
  if (idx >= Lsteps * 129024) return;
  int l = idx / 129024;
  int r = idx - l * 129024;
  int tap = r / 14336;
  int r2 = r - tap * 14336;
  int kc = r2 / 3584;
  int r3 = r2 - kc * 3584;
  int o = r3 >> 9;
  int r4 = r3 & 511;
  int lane = r4 >> 3;
  int j = r4 & 7;
  int q = lane >> 4, n = lane & 15;
  int oc = o * 16 + n;
  int ic = (kc < 3 ? kc * 32 : 72) + q * 8 + j;
  bool real = (oc < 100) && (kc < 3 ? true : (ic >= 96 && ic < 100));
  float v = real ? w2[l * 90000 + oc * 900 + ic * 9 + tap] : 0.f;
  w2b[idx] = bf16r(v);
}

// w3p[l][tap][ic] fp32, ic zero-padded to 128
__global__ void w3p_prep(const float* __restrict__ w3, float* __restrict__ w3p) {
  int idx = blockIdx.x * 256 + threadIdx.x;     // 5760
  if (idx >= Lsteps * 9 * 128) return;
  int l = idx / 1152;
  int r = idx - l * 1152;
  int tap = r >> 7;
  int ic = r & 127;
  w3p[idx] = (ic < 100) ? w3[l * 900 + ic * 9 + tap] : 0.f;
}

// MERGED field_fused + conv12 (role-split grid). Both paths read only
// img/res_i(/tgt); field writes grads+fields, conv12 writes x2 -> no
// hazard, bit-identical outputs. field's VALU/LDS work backfills conv12's
// stall slack (conv12 pipes all <=60% busy) instead of running serially.
// Grid: 512 field blocks first (drain early), then 4096 conv12 blocks.
// Shared LDS union 37.44 KB (field path uses 29.44 KB) -> 4 blocks/CU.
// launch_bounds(256,4) caps VGPR+AGPR at 128 (r9 lesson: 16-wave budget).
__global__ __launch_bounds__(256, 4) void fc_kernel(
    const float* __restrict__ res_i, const float* __restrict__ img,
    const float* __restrict__ tgt, const float* __restrict__ w1,
    const short8* __restrict__ w2b, ushort* __restrict__ x2,
    float* __restrict__ grads_i, float* __restrict__ fields_i) {
  __shared__ __align__(16) uint smem[9360];   // 37440 B
  const int tid = threadIdx.x;
  const int bx = blockIdx.x;

  if (bx < 512) {
    // ---------------- field path (sobel + vblur + hblur) ----------------
    float* sBuf = (float*)smem;          // 2560 f
    float* sP0 = sBuf + 2560;            // 2400 f
    float* sP1 = sP0 + 2400;             // 2400 f
    const int b = bx >> 6;
    const int Y0 = ((bx >> 2) & 15) * 16, X0 = (bx & 3) * 64;
    float G[15]; make_gauss(G);
    const float* ib = img + b * HWn;
    const float* rb = res_i + b * HWn;

    // stage img rows Y0-8..Y0+23, cols X0-8..X0+71, clamped (replicate pad)
    for (int u = tid; u < 2560; u += 256) {
      int ly = u / 80, lx = u - ly * 80;
      int gy = Y0 - 8 + ly, gx = X0 - 8 + lx;
      gy = gy < 0 ? 0 : (gy > 255 ? 255 : gy);
      gx = gx < 0 ? 0 : (gx > 255 ? 255 : gx);
      sBuf[u] = ib[gy * 256 + gx];
    }
    __syncthreads();

    // p = -res * sobel(img); rows Y0-7..Y0+22 (30), cols X0-7..X0+70
    for (int u = tid; u < 2400; u += 256) {
      int ly = u / 80, lx = u - ly * 80;
      int gy = Y0 - 7 + ly, gx = X0 - 7 + lx;
      float p0 = 0.f, p1 = 0.f;
      if (lx < 78 && (unsigned)gy < 256u && (unsigned)gx < 256u) {
        int base = (ly + 1) * 80 + (lx + 1);
        float a00 = sBuf[base - 81], a01 = sBuf[base - 80], a02 = sBuf[base - 79];
        float a10 = sBuf[base - 1], a12 = sBuf[base + 1];
        float a20 = sBuf[base + 79], a21 = sBuf[base + 80], a22 = sBuf[base + 81];
        float gxs = (a02 - a00 + 2.f * (a12 - a10) + a22 - a20) * 0.125f;
        float gys = (a20 - a00 + 2.f * (a21 - a01) + a22 - a02) * 0.125f;
        float r = rb[gy * 256 + gx];
        p0 = -r * gxs; p1 = -r * gys;
        if (ly >= 7 && ly < 23 && lx >= 7 && lx < 71) {   // owned pixel
          grads_i[b * 131072 + gy * 256 + gx] = gxs;
          grads_i[b * 131072 + 65536 + gy * 256 + gx] = gys;
        }
      }
      sP0[u] = p0; sP1[u] = p1;
    }
    __syncthreads();

    // vertical blur -> t (overlays sBuf): 2ch x 16 rows x 80 cols
    for (int u = tid; u < 2560; u += 256) {
      int c = u >= 1280 ? 1 : 0;
      int v = u - c * 1280;
      int ly = v / 80, lx = v - ly * 80;
      float s = 0.f;
      if (lx < 78) {
        const float* pc = (c ? sP1 : sP0) + ly * 80 + lx;
#pragma unroll
        for (int t = 0; t < 15; t++) s += G[t] * pc[t * 80];
      }
      sBuf[u] = s;
    }
    __syncthreads();

    // horizontal blur -> fields (interleaved 2ch)
    for (int u = tid; u < 2048; u += 256) {
      int c = u >> 10, v = u & 1023;
      int ly = v >> 6, lx = v & 63;
      const float* tc = sBuf + c * 1280 + ly * 80 + lx;
      float s = 0.f;
#pragma unroll
      for (int t = 0; t < 15; t++) s += G[t] * tc[t];
      int gy = Y0 + ly, gx = X0 + lx;
      fields_i[(b * 65536 + gy * 256 + gx) * 2 + c] = s;
    }
    return;
  }

  // ---------------- conv12 path (r7-best structure, 197us) ----------------
  ushort* x1s = (ushort*)smem;           // 180*104 ushorts = 37440 B
  const int cid = bx - 512;
  const int b = cid >> 9;
  const int Y0 = ((cid >> 4) & 31) * 8, X0 = (cid & 15) * 16;
  const float* zb = res_i + b * HWn;
  const float* ib = img + b * HWn;
  const float* tb = tgt + b * HWn;

  // ---- Phase A: conv1 (3->100) + lrelu -> bf16 LDS (104-wide rows) ----
  if (tid < 180) {
    int ly = tid / 18, lx = tid - ly * 18;
    int gy = Y0 + ly - 1, gx = X0 + lx - 1;
    const bool inb = (unsigned)gy < 256u && (unsigned)gx < 256u;
    float p[27];
#pragma unroll
    for (int dy = 0; dy < 3; dy++)
#pragma unroll
      for (int dx = 0; dx < 3; dx++) {
        int yy = gy + dy - 1, xx = gx + dx - 1;
        bool ok = (unsigned)yy < 256u && (unsigned)xx < 256u;
        int o = ok ? (yy * 256 + xx) : 0;
        int j = dy * 3 + dx;
        p[j] = ok ? zb[o] : 0.f;
        p[9 + j] = ok ? ib[o] : 0.f;
        p[18 + j] = ok ? tb[o] : 0.f;
      }
    const uint base = (uint)tid * 104u;
    for (int oc = 0; oc < 100; oc += 2) {
      const float* wa = w1 + oc * 27;
      float s0 = 0.f, s1 = 0.f;
#pragma unroll
      for (int j = 0; j < 27; j++) {
        s0 = fmaf(p[j], wa[j], s0);
        s1 = fmaf(p[j], wa[27 + j], s1);
      }
      s0 = inb ? lrelu(s0) : 0.f;
      s1 = inb ? lrelu(s1) : 0.f;
      *(uint*)&x1s[base + oc] = (uint)bf16r(s0) | ((uint)bf16r(s1) << 16);
    }
    *(uint*)&x1s[base + 100] = 0u;
    *(uint*)&x1s[base + 102] = 0u;
  }
  __syncthreads();

  // ---- Phase B: conv2 via bf16 MFMA, oc-split across waves ----
  const int lane = tid & 63, wv = tid >> 6;
  const int q = lane >> 4, n = lane & 15;
  f32x4 acc[8][2];
#pragma unroll
  for (int r = 0; r < 8; r++)
#pragma unroll
    for (int f = 0; f < 2; f++) acc[r][f] = (f32x4)(0.f);

  // wave w loads fragments o = 2w, 2w+1 only (disjoint across waves)
  const short8* wsrc = w2b + lane + (uint)(wv * 2) * 64u;
  auto loadw = [&](short8 (&dst)[2], int it) {
    const short8* s = wsrc + (it >> 2) * 1792 + (it & 3) * 448;
    dst[0] = s[0];
    dst[1] = s[64];   // for wv==3 this is a dead fragment (never stored)
  };
  auto compute = [&](short8 (&w)[2], int it) {
    const int tap = it >> 2, kc = it & 3;
    const int dy = tap / 3, dx = tap - dy * 3;
    const int koff = (kc < 3 ? kc * 32 : 72) + q * 8;   // tail chunk at ch 72..103
    const uint abase = (uint)(dy * 18 + n + dx) * 104u + (uint)koff;
    __builtin_amdgcn_s_setprio(1);
#pragma unroll
    for (int r = 0; r < 8; r++) {
      short8 a = *(const short8*)&x1s[abase + (uint)r * 1872u];   // row stride 18*104
      acc[r][0] = __builtin_amdgcn_mfma_f32_16x16x32_bf16(a, w[0], acc[r][0], 0, 0, 0);
      acc[r][1] = __builtin_amdgcn_mfma_f32_16x16x32_bf16(a, w[1], acc[r][1], 0, 0, 0);
    }
    __builtin_amdgcn_s_setprio(0);
  };

  short8 wA[2], wB[2];
  loadw(wA, 0);
#pragma unroll
  for (int it = 0; it < 36; it += 2) {
    loadw(wB, it + 1);        // prefetch while computing on wA
    compute(wA, it);
    if (it + 2 < 36) loadw(wA, it + 2);
    compute(wB, it + 1);
  }

  // ---- Epilogue: acc -> LDS [pix(y*16+x)][104] bf16 -> coalesced stores ----
  __syncthreads();   // everyone done reading x1s; safe to repurpose
#pragma unroll
  for (int f = 0; f < 2; f++) {
    const int o = wv * 2 + f;
    if (o < 7) {
      const int oc = o * 16 + n;
      if (oc < 104) {                      // oc 100..103: acc==0 (zero-padded w2b)
#pragma unroll
        for (int r = 0; r < 8; r++) {
#pragma unroll
          for (int v = 0; v < 4; v++) {
            const int pix = r * 16 + q * 4 + v;
            x1s[pix * 104 + oc] = bf16r(lrelu(acc[r][f][v]));
          }
        }
      }
    }
  }
  __syncthreads();
  ushort* xg = x2 + (size_t)((b << 16) + Y0 * 256 + X0) * 104;
  for (int u = tid; u < 1664; u += 256) {   // 128 pixels * 13 uint4
    int pix = u / 13, ch = u - pix * 13;
    int y = pix >> 4, x = pix & 15;
    uint4 val = *(const uint4*)&x1s[pix * 104 + ch * 8];
    *(uint4*)(xg + (size_t)(y * 256 + x) * 104 + ch * 8) = val;
  }
}

// conv3 (100->1, LDS-tiled channels-last bf16 x2) + residual update.
// Block = 16x16 output pixels; x2 halo tile 18x18 px staged once into LDS.
__global__ __launch_bounds__(256, 2) void conv3res_kernel(
    const float* __restrict__ res_i,
    const ushort* __restrict__ x2,
    const float* __restrict__ w3p,
    float* __restrict__ res_n) {
  __shared__ ushort sx[324 * 104];   // [18*18 px][104 ch], px stride 208B (16B-aligned)
  const int tid = threadIdx.x;
  const int b = blockIdx.z;
  const int Y0 = blockIdx.y * 16, X0 = blockIdx.x * 16;

  // stage x2 tile + halo (zeros outside image)
  for (int u = tid; u < 4212; u += 256) {     // 324 px * 13 uint4
    int pix = u / 13, ch = u - pix * 13;
    int py = pix / 18, px = pix - py * 18;
    int gy = Y0 - 1 + py, gx = X0 - 1 + px;
    uint4 v = make_uint4(0u, 0u, 0u, 0u);
    if ((unsigned)gy < 256u && (unsigned)gx < 256u)
      v = *(const uint4*)(x2 + (size_t)((b << 16) + gy * 256 + gx) * 104 + ch * 8);
    *(uint4*)&sx[pix * 104 + ch * 8] = v;
  }
  __syncthreads();

  const int ly = tid >> 4, lx = tid & 15;
  const int y = Y0 + ly, x = X0 + lx;
  const int idx = (b << 16) + y * 256 + x;

  float acc = 0.f;
#pragma unroll
  for (int tap = 0; tap < 9; tap++) {
    int dy = tap / 3, dx = tap - dy * 3;
    const ushort* px_ = &sx[((ly + dy) * 18 + (lx + dx)) * 104];
    const float* wt = w3p + tap * 128;
#pragma unroll
    for (int c = 0; c < 13; c++) {   // 104 channels; 100..103 stored as zero
      uint4 u = *(const uint4*)(px_ + c * 8);
      const float* w8 = wt + c * 8;
      acc = fmaf(__uint_as_float(u.x << 16), w8[0], acc);
      acc = fmaf(__uint_as_float(u.x & 0xffff0000u), w8[1], acc);
      acc = fmaf(__uint_as_float(u.y << 16), w8[2], acc);
      acc = fmaf(__uint_as_float(u.y & 0xffff0000u), w8[3], acc);
      acc = fmaf(__uint_as_float(u.z << 16), w8[4], acc);
      acc = fmaf(__uint_as_float(u.z & 0xffff0000u), w8[5], acc);
      acc = fmaf(__uint_as_float(u.w << 16), w8[6], acc);
      acc = fmaf(__uint_as_float(u.w & 0xffff0000u), w8[7], acc);
    }
  }
  res_n[idx] = res_i[idx] - 0.2f * acc;
}

// phi chain + image update. No LDS -> high occupancy: the scattered
// bilin1/bilin2 gathers are latency-bound.
__global__ __launch_bounds__(256) void phiimg_kernel(
    const float* __restrict__ fields_i,
    const float* __restrict__ phi_src,
    float* __restrict__ phi_dst,
    const float* __restrict__ source,
    const float* __restrict__ res_base,
    const float* __restrict__ res_n,
    float* __restrict__ img_out, int step) {
  int idx = blockIdx.x * 256 + threadIdx.x;   // 524288
  int b = idx >> 16, y = (idx >> 8) & 255, x = idx & 255;
  int pix2 = (y * 256 + x) * 2;
  float f0 = fields_i[2 * idx], f1 = fields_i[2 * idx + 1];
  float dxp = (float)x - f0 * 0.2f;
  float dyp = (float)y - f1 * 0.2f;
  float img = 0.f, rs = res_n[idx];
  for (int k = 0; k <= step; k++) {
    float o0, o1;
    if (k == step) { o0 = dxp; o1 = dyp; }
    else bilin2(phi_src + (size_t)(k * 8 + b) * 131072, dxp, dyp, o0, o1);
    float* dst = phi_dst + (size_t)(k * 8 + b) * 131072 + pix2;
    dst[0] = o0; dst[1] = o1;
    if (k == 0) img = bilin1(source + b * HWn, o0, o1);
    else rs += bilin1(res_base + (size_t)k * BHW + b * HWn, o0, o1);
  }
  img_out[idx] = img + rs * 8.0e-5f;
}

extern "C" void kernel_launch(void* const* d_in, const int* in_sizes, int n_in,
                              void* d_out, int out_size, void* d_ws, size_t ws_size,
                              hipStream_t stream) {
  const float* source = (const float*)d_in[0];
  const float* target = (const float*)d_in[1];
  const float* z0 = (const float*)d_in[3];
  const float* w1 = (const float*)d_in[4];
  const float* w2 = (const float*)d_in[5];
  const float* w3 = (const float*)d_in[6];
  float* out = (float*)d_out;
  float* ws = (float*)d_ws;

  float* ws_img = ws + WS_IMG;
  float* phiA = ws + WS_PHIA;
  float* phiB = ws + WS_PHIB;
  ushort* w2b = (ushort*)(ws + WS_W2B);
  float* w3p = ws + WS_W3P;
  ushort* x2 = (ushort*)(ws + WS_X2);

  hipMemcpyAsync(ws_img, source, BHW * sizeof(float), hipMemcpyDeviceToDevice, stream);
  init_res0_kernel<<<BHW / 256, 256, 0, stream>>>(z0, out + OUT_RES);
  w2b_prep<<<(Lsteps * 129024 + 255) / 256, 256, 0, stream>>>(w2, w2b);
  w3p_prep<<<23, 256, 0, stream>>>(w3, w3p);

  for (int i = 0; i < Lsteps; i++) {
    float* grads_i = out + OUT_GRADS + (size_t)i * 1048576;
    float* fields_i = out + OUT_FIELDS + (size_t)i * 1048576;
    const float* res_i = out + OUT_RES + (size_t)i * BHW;
    float* res_n = out + OUT_RES + (size_t)(i + 1) * BHW;
    float* phi_dst = (i % 2 == 0) ? phiA : phiB;
    float* phi_src = (i % 2 == 0) ? phiB : phiA;

    fc_kernel<<<4608, 256, 0, stream>>>(
        res_i, ws_img, target, w1 + i * 2700,
        (const short8*)(w2b + (size_t)i * 129024), x2, grads_i, fields_i);
    conv3res_kernel<<<dim3(16, 16, 8), 256, 0, stream>>>(
        res_i, x2, w3p + i * 1152, res_n);
    phiimg_kernel<<<BHW / 256, 256, 0, stream>>>(
        fields_i, phi_src, phi_dst, source, out + OUT_RES, res_n, ws_img, i);
  }
  hipMemcpyAsync(out + OUT_IMG, ws_img, BHW * sizeof(float), hipMemcpyDeviceToDevice, stream);
}